// Round 11
// baseline (319.307 us; speedup 1.0000x reference)
//
#include <hip/hip_runtime.h>
#include <stdint.h>

// ---------------------------------------------------------------------------
// Attention_53790170415368 : NAG dual-SDPA attention block, MI355X / gfx950
// R11: k_attn launch_bounds(256,4) (LDS 40KB x 4 = exactly 160KB/CU -> 4
//      blocks/CU capacity, no launch tail at 640 blocks); GEMM2 gets the
//      XCD-bijective block swizzle. Everything else unchanged from R10.
// ---------------------------------------------------------------------------

typedef short s8x __attribute__((ext_vector_type(8)));   // 8 x bf16 (raw bits)
typedef float f4x __attribute__((ext_vector_type(4)));
typedef unsigned short u16;

#define NDIM   2048
#define NHEAD  16
#define NHD    128
#define NSEQ   2560
#define NSDPA  2304

__device__ __forceinline__ u16 f2bf(float f) {
  union { float f; unsigned u; } v; v.f = f;
  unsigned r = v.u + 0x7FFFu + ((v.u >> 16) & 1u);   // RNE
  return (u16)(r >> 16);
}

__device__ __forceinline__ float bf2f(unsigned hi16_in_place) {
  union { unsigned u; float f; } v; v.u = hi16_in_place;
  return v.f;
}

__device__ __forceinline__ void gload16(const void* g, void* l) {
  __builtin_amdgcn_global_load_lds(
      (const __attribute__((address_space(1))) unsigned*)g,
      (__attribute__((address_space(3))) unsigned*)l, 16, 0, 0);
}

// ---- merged fp32 -> bf16 casts: h (2560 blks) + 4 weights (4x2048 blks) -----
__global__ void k_cast(const float* __restrict__ h, const float* __restrict__ w0,
                       const float* __restrict__ w1, const float* __restrict__ w2,
                       const float* __restrict__ w3, u16* __restrict__ hB,
                       u16* __restrict__ wB) {
  int bid = blockIdx.x;
  const float* src; u16* dst; int i;
  if (bid < 2560) {                       // h: 655360 groups of 8
    src = h; dst = hB; i = bid * 256 + threadIdx.x;
  } else {
    int b = bid - 2560;
    int m = b >> 11;                      // /2048
    i = (b & 2047) * 256 + threadIdx.x;   // 0..524287
    src = (m == 0) ? w0 : (m == 1) ? w1 : (m == 2) ? w2 : w3;
    dst = wB + (size_t)m * 4194304;
  }
  const float4* s4 = (const float4*)src + (size_t)i * 2;
  float4 a = s4[0], b4 = s4[1];
  uint4 p;
  p.x = (unsigned)f2bf(a.x) | ((unsigned)f2bf(a.y) << 16);
  p.y = (unsigned)f2bf(a.z) | ((unsigned)f2bf(a.w) << 16);
  p.z = (unsigned)f2bf(b4.x) | ((unsigned)f2bf(b4.y) << 16);
  p.w = (unsigned)f2bf(b4.z) | ((unsigned)f2bf(b4.w) << 16);
  *(uint4*)(dst + (size_t)i * 8) = p;
}

// ---- C[M,N] f32 = A[M,K]bf16 @ B[N,K]bf16^T  (m97, 128x128, XCD swizzle) ----
__global__ __launch_bounds__(256, 2)
void k_gemm_bt(const u16* __restrict__ A, const u16* __restrict__ B,
               float* __restrict__ C, int K, int ldc, int nbn) {
  __shared__ __align__(16) unsigned char sm[16384];  // A tile 8K | B tile 8K
  const int cpx = gridDim.x >> 3;
  const int f = blockIdx.x;
  const int swz = (f & 7) * cpx + (f >> 3);          // bijective: grid % 8 == 0
  const int bm = (swz / nbn) * 128, bn = (swz % nbn) * 128;
  const int lane = threadIdx.x & 63, wl = threadIdx.x >> 6;
  const int wm = wl >> 1, wn = wl & 1;
  const int g = lane >> 4, li = lane & 15;
  f4x acc[4][4] = {};
  const int nk = K >> 5;
  for (int kk = 0; kk < nk; ++kk) {
#pragma unroll
    for (int c = 0; c < 2; ++c) {
      int base = (wl * 2 + c) * 1024;
      int row = (base >> 6) + (lane >> 2);
      int colb = (lane & 3) * 16;
      gload16((const char*)A + ((size_t)(bm + row) * K + kk * 32) * 2 + colb, sm + base);
      gload16((const char*)B + ((size_t)(bn + row) * K + kk * 32) * 2 + colb, sm + 8192 + base);
    }
    __syncthreads();
    s8x a[4];
#pragma unroll
    for (int mt = 0; mt < 4; ++mt)
      a[mt] = *(const s8x*)(sm + (wm * 64 + mt * 16 + li) * 64 + g * 16);
#pragma unroll
    for (int nt = 0; nt < 4; ++nt) {
      s8x b = *(const s8x*)(sm + 8192 + (wn * 64 + nt * 16 + li) * 64 + g * 16);
#pragma unroll
      for (int mt = 0; mt < 4; ++mt)
        acc[mt][nt] = __builtin_amdgcn_mfma_f32_16x16x32_bf16(a[mt], b, acc[mt][nt], 0, 0, 0);
    }
    __syncthreads();
  }
#pragma unroll
  for (int mt = 0; mt < 4; ++mt)
#pragma unroll
    for (int nt = 0; nt < 4; ++nt)
#pragma unroll
      for (int r = 0; r < 4; ++r) {
        int row = bm + wm * 64 + mt * 16 + g * 4 + r;
        int col = bn + wn * 64 + nt * 16 + li;
        C[(size_t)row * ldc + col] = acc[mt][nt][r];
      }
}

// ---- 256x256 tile, BK=64, 8 waves (2Mx4N), 128KB LDS dbuf, 4-phase/tile -----
// Writes bf16 output. LDS slot (64KB): A [256][64]bf16 swz @0, B @32KB.
__device__ __forceinline__ void stageAB256(const u16* __restrict__ M, int K,
                                           int row0, int kk, unsigned char* dst,
                                           int tid) {
#pragma unroll
  for (int c = 0; c < 4; ++c) {
    int idx = c * 512 + tid;                 // chunk 0..2047 (row r, chunk idx&7)
    int r = idx >> 3, cc = idx & 7;
    gload16(M + (size_t)(row0 + r) * K + kk + ((cc ^ (r & 7)) * 8), dst + idx * 16);
  }
}

#define G256_SYNC() do { __builtin_amdgcn_s_barrier();                        \
    asm volatile("s_waitcnt lgkmcnt(0)" ::: "memory");                        \
    __builtin_amdgcn_sched_barrier(0); } while (0)

__global__ __launch_bounds__(512, 2)
void k_gemm256(const u16* __restrict__ A, const u16* __restrict__ B,
               u16* __restrict__ C, int K, int ldc, int nbn) {
  extern __shared__ __align__(16) unsigned char sm[];     // 131072
  const int tid = threadIdx.x;
  const int lane = tid & 63, wid = tid >> 6;
  const int g = lane >> 4, li = lane & 15;
  const int wr = wid >> 2, wc = wid & 3;

  const int cpx = gridDim.x >> 3;
  const int f = blockIdx.x;
  const int swz = (f & 7) * cpx + (f >> 3);
  const int bm = (swz / nbn) * 256, bn = (swz % nbn) * 256;

  f4x acc[8][4] = {};
  const int nk = K >> 6;

  stageAB256(A, K, bm, 0, sm, tid);
  stageAB256(B, K, bn, 0, sm + 32768, tid);
  stageAB256(A, K, bm, 64, sm + 65536, tid);
  stageAB256(B, K, bn, 64, sm + 98304, tid);
  asm volatile("s_waitcnt vmcnt(8)" ::: "memory");
  __builtin_amdgcn_s_barrier();

  for (int t = 0; t < nk; ++t) {
    unsigned char* sA = sm + (t & 1) * 65536;
    unsigned char* sB = sA + 32768;
    s8x a[8][2], b[4][2];

#pragma unroll
    for (int mt = 0; mt < 4; ++mt) {
      int r = wr * 128 + mt * 16 + li;
#pragma unroll
      for (int ks = 0; ks < 2; ++ks)
        a[mt][ks] = *(const s8x*)(sA + r * 128 + (((ks * 4 + g) ^ (r & 7)) * 16));
    }
#pragma unroll
    for (int nt = 0; nt < 4; ++nt) {
      int r = wc * 64 + nt * 16 + li;
      b[nt][0] = *(const s8x*)(sB + r * 128 + ((g ^ (r & 7)) * 16));
    }
    G256_SYNC();
    __builtin_amdgcn_s_setprio(1);
#pragma unroll
    for (int nt = 0; nt < 4; ++nt)
#pragma unroll
      for (int mt = 0; mt < 4; ++mt)
        acc[mt][nt] = __builtin_amdgcn_mfma_f32_16x16x32_bf16(a[mt][0], b[nt][0], acc[mt][nt], 0, 0, 0);
    __builtin_amdgcn_s_setprio(0);
    __builtin_amdgcn_s_barrier();

#pragma unroll
    for (int mt = 4; mt < 8; ++mt) {
      int r = wr * 128 + mt * 16 + li;
#pragma unroll
      for (int ks = 0; ks < 2; ++ks)
        a[mt][ks] = *(const s8x*)(sA + r * 128 + (((ks * 4 + g) ^ (r & 7)) * 16));
    }
#pragma unroll
    for (int nt = 0; nt < 4; ++nt) {
      int r = wc * 64 + nt * 16 + li;
      b[nt][1] = *(const s8x*)(sB + r * 128 + (((4 + g) ^ (r & 7)) * 16));
    }
    G256_SYNC();
    __builtin_amdgcn_s_setprio(1);
#pragma unroll
    for (int nt = 0; nt < 4; ++nt)
#pragma unroll
      for (int mt = 4; mt < 8; ++mt)
        acc[mt][nt] = __builtin_amdgcn_mfma_f32_16x16x32_bf16(a[mt][0], b[nt][0], acc[mt][nt], 0, 0, 0);
    __builtin_amdgcn_s_setprio(0);
    __builtin_amdgcn_s_barrier();

    if (t + 2 < nk) stageAB256(A, K, bm, (t + 2) * 64, sA, tid);
    G256_SYNC();
    __builtin_amdgcn_s_setprio(1);
#pragma unroll
    for (int nt = 0; nt < 4; ++nt)
#pragma unroll
      for (int mt = 0; mt < 4; ++mt)
        acc[mt][nt] = __builtin_amdgcn_mfma_f32_16x16x32_bf16(a[mt][1], b[nt][1], acc[mt][nt], 0, 0, 0);
    __builtin_amdgcn_s_setprio(0);
    __builtin_amdgcn_s_barrier();

    if (t + 2 < nk) stageAB256(B, K, bn, (t + 2) * 64, sB, tid);
    G256_SYNC();
    __builtin_amdgcn_s_setprio(1);
#pragma unroll
    for (int nt = 0; nt < 4; ++nt)
#pragma unroll
      for (int mt = 4; mt < 8; ++mt)
        acc[mt][nt] = __builtin_amdgcn_mfma_f32_16x16x32_bf16(a[mt][1], b[nt][1], acc[mt][nt], 0, 0, 0);
    __builtin_amdgcn_s_setprio(0);
    if (t + 1 < nk) {
      if (t + 2 < nk) asm volatile("s_waitcnt vmcnt(8)" ::: "memory");
      else            asm volatile("s_waitcnt vmcnt(0)" ::: "memory");
      __builtin_amdgcn_s_barrier();
    }
  }

#pragma unroll
  for (int mt = 0; mt < 8; ++mt)
#pragma unroll
    for (int nt = 0; nt < 4; ++nt)
#pragma unroll
      for (int rr = 0; rr < 4; ++rr) {
        int row = bm + wr * 128 + mt * 16 + g * 4 + rr;
        int col = bn + wc * 64 + nt * 16 + li;
        C[(size_t)row * ldc + col] = f2bf(acc[mt][nt][rr]);
      }
}

// ---- merged prep: rmsnorm+rope (blocks <10240) | v-transpose (blocks >=10240)
__global__ void k_prep(const u16* __restrict__ qkv, const float* __restrict__ nqw,
                       const float* __restrict__ nkw, const float* __restrict__ fc,
                       u16* __restrict__ qh, u16* __restrict__ kh,
                       u16* __restrict__ vT) {
  __shared__ u16 t[128][65];
  int bid = blockIdx.x;
  if (bid < 10240) {
    int wid = threadIdx.x >> 6, lane = threadIdx.x & 63;
    int pair = bid * 4 + wid;               // 0 .. 40959
    int s = pair >> 4, hh = pair & 15;
    const u16* qrow = qkv + (size_t)s * 6144 + hh * 128;
    unsigned uq = *(const unsigned*)(qrow + lane * 2);
    unsigned uk = *(const unsigned*)(qrow + 2048 + lane * 2);
    float qx = bf2f(uq << 16), qy = bf2f(uq & 0xFFFF0000u);
    float kx = bf2f(uk << 16), ky = bf2f(uk & 0xFFFF0000u);
    float sq = qx * qx + qy * qy;
    float sk = kx * kx + ky * ky;
#pragma unroll
    for (int m = 32; m >= 1; m >>= 1) { sq += __shfl_xor(sq, m); sk += __shfl_xor(sk, m); }
    float rq = rsqrtf(sq * (1.f / 128.f) + 1e-5f);
    float rk = rsqrtf(sk * (1.f / 128.f) + 1e-5f);
    float2 wq2 = *(const float2*)(nqw + lane * 2);
    float2 wk2 = *(const float2*)(nkw + lane * 2);
    float2 cs = *(const float2*)(fc + (size_t)s * 128 + lane * 2);
    float q0 = qx * rq * wq2.x, q1 = qy * rq * wq2.y;
    float k0 = kx * rk * wk2.x, k1 = ky * rk * wk2.y;
    unsigned qo = (unsigned)f2bf(q0 * cs.x - q1 * cs.y) | ((unsigned)f2bf(q1 * cs.x + q0 * cs.y) << 16);
    unsigned ko = (unsigned)f2bf(k0 * cs.x - k1 * cs.y) | ((unsigned)f2bf(k1 * cs.x + k0 * cs.y) << 16);
    *(unsigned*)(qh + ((size_t)hh * NSEQ + s) * 128 + lane * 2) = qo;
    *(unsigned*)(kh + ((size_t)hh * NSEQ + s) * 128 + lane * 2) = ko;
    return;
  }
  int bx = bid - 10240;                      // 0..639: 40 s-blocks x 16 heads
  int s0 = (bx % 40) * 64, hh = bx / 40;
  int tid = threadIdx.x;
#pragma unroll
  for (int rep = 0; rep < 16; ++rep) {
    int idx = rep * 256 + tid;               // (row sr, u32-pair d2)
    int sr = idx >> 6, d2 = idx & 63;
    unsigned v2 = *(const unsigned*)(qkv + (size_t)(s0 + sr) * 6144 + 4096 + hh * 128 + d2 * 2);
    t[d2 * 2][sr] = (u16)v2;
    t[d2 * 2 + 1][sr] = (u16)(v2 >> 16);
  }
  __syncthreads();
#pragma unroll
  for (int rep = 0; rep < 16; ++rep) {
    int idx = rep * 256 + tid; int d = idx >> 5, sc2 = (idx & 31) * 2;
    unsigned val = (unsigned)t[d][sc2] | ((unsigned)t[d][sc2 + 1] << 16);
    *(unsigned*)(vT + ((size_t)hh * 128 + d) * NSEQ + s0 + sc2) = val;
  }
}

// ---- flash attention helpers ------------------------------------------------
// LDS (40960 B): K [64][128]swz @0 (16K) | vT [128][64]swz @16K (16K) | P @32K
__device__ __forceinline__ void stage_kv(const u16* __restrict__ khh,
                                         const u16* __restrict__ vTh,
                                         int kphys, unsigned char* sm,
                                         int lane, int wl) {
#pragma unroll
  for (int c = 0; c < 4; ++c) {
    int base = (wl * 4 + c) * 1024;
    { int row = (base >> 8) + (lane >> 4);                 // K tile: 64 rows x 256B
      int src = ((lane & 15) * 16) ^ ((row & 7) << 4);
      gload16((const char*)(khh + (size_t)(kphys + row) * 128) + src, sm + base); }
    { int row = (base >> 7) + (lane >> 3);                 // vT tile: 128 rows x 128B
      int src = ((lane & 7) * 16) ^ ((row & 7) << 4);
      gload16((const char*)(vTh + (size_t)row * NSEQ + kphys) + src, sm + 16384 + base); }
  }
}

// o[0..7] = output d-columns, o[8] = softmax denominator (MFMA-of-ones column).
__device__ __forceinline__ void tile_compute(unsigned char* sm, unsigned char* pb,
                                             const s8x (&aq)[4], int g, int li,
                                             f4x (&o)[9], float (&mold)[4]) {
  const float S2 = 0.08838834764831845f * 1.4426950408889634f;  // scale*log2(e)
  const float THR_RAW = 90.0f;                 // ~8 in exp-arg units
  const s8x PONE = {16256, 16256, 16256, 16256, 16256, 16256, 16256, 16256}; // bf16 1.0
  const f4x zf = {0.f, 0.f, 0.f, 0.f};
  f4x sc[4];
#pragma unroll
  for (int nt = 0; nt < 4; ++nt) sc[nt] = zf;
  __builtin_amdgcn_s_setprio(1);
#pragma unroll
  for (int nt = 0; nt < 4; ++nt) {
    int row = nt * 16 + li;
    int rx = (row & 7) << 4;
#pragma unroll
    for (int ds = 0; ds < 4; ++ds) {
      s8x bk = *(const s8x*)(sm + row * 256 + ((ds * 64 + g * 16) ^ rx));
      sc[nt] = __builtin_amdgcn_mfma_f32_16x16x32_bf16(aq[ds], bk, sc[nt], 0, 0, 0);
    }
  }
  __builtin_amdgcn_s_setprio(0);

  float tl[4];
#pragma unroll
  for (int r = 0; r < 4; ++r)
    tl[r] = fmaxf(fmaxf(sc[0][r], sc[1][r]), fmaxf(sc[2][r], sc[3][r]));
  bool need = (tl[0] > mold[0] + THR_RAW) || (tl[1] > mold[1] + THR_RAW) ||
              (tl[2] > mold[2] + THR_RAW) || (tl[3] > mold[3] + THR_RAW);
  if (__any((int)need)) {
#pragma unroll
    for (int r = 0; r < 4; ++r) {
      float t = tl[r];
#pragma unroll
      for (int msk = 8; msk >= 1; msk >>= 1) t = fmaxf(t, __shfl_xor(t, msk));
      float mn = fmaxf(mold[r], t);
      float corr = exp2f((mold[r] - mn) * S2);
      mold[r] = mn;
#pragma unroll
      for (int dt = 0; dt < 9; ++dt) o[dt][r] *= corr;
    }
  }
  float nb[4];
#pragma unroll
  for (int r = 0; r < 4; ++r) nb[r] = -mold[r] * S2;
#pragma unroll
  for (int nt = 0; nt < 4; ++nt) {             // P A-layout [16 q][64 key] swz
    int colb = (nt * 16 + li) * 2;
#pragma unroll
    for (int r = 0; r < 4; ++r) {
      float p = exp2f(fmaf(sc[nt][r], S2, nb[r]));
      union { float f; unsigned u; } pv_; pv_.f = p;
      int q = g * 4 + r;
      *(u16*)(pb + q * 128 + (colb ^ ((q & 7) << 4))) = (u16)(pv_.u >> 16);
    }
  }
  __builtin_amdgcn_s_setprio(1);
#pragma unroll
  for (int ks = 0; ks < 2; ++ks) {
    s8x pa = *(const s8x*)(pb + li * 128 + ((ks * 64 + g * 16) ^ ((li & 7) << 4)));
#pragma unroll
    for (int dt = 0; dt < 8; ++dt) {
      int row = dt * 16 + li;
      s8x bv = *(const s8x*)(sm + 16384 + row * 128 + ((ks * 64 + g * 16) ^ ((row & 7) << 4)));
      o[dt] = __builtin_amdgcn_mfma_f32_16x16x32_bf16(pa, bv, o[dt], 0, 0, 0);
    }
    o[8] = __builtin_amdgcn_mfma_f32_16x16x32_bf16(pa, PONE, o[8], 0, 0, 0);
  }
  __builtin_amdgcn_s_setprio(0);
}

__device__ __forceinline__ void epilogue(u16* __restrict__ out, int q0, int hh,
                                         int g, int li, const f4x (&o)[9]) {
  float inv[4];
#pragma unroll
  for (int r = 0; r < 4; ++r) inv[r] = 1.f / o[8][r];
#pragma unroll
  for (int dt = 0; dt < 8; ++dt)
#pragma unroll
    for (int r = 0; r < 4; ++r) {
      int n = q0 + g * 4 + r;
      int col = hh * 128 + dt * 16 + li;
      out[(size_t)n * NDIM + col] = f2bf(o[dt][r] * inv[r]);
    }
}

// ---- fused pos/neg flash attention ------------------------------------------
// 640 blocks, 256 thr (4 waves), 64 q-rows/WG (16/wave). XCD x: heads {2x,2x+1}.
// LDS 40KB x 4 blocks/CU = 160KB exactly.
__global__ __launch_bounds__(256, 4)
void k_attn(const u16* __restrict__ qh, const u16* __restrict__ kh,
            const u16* __restrict__ vT, u16* __restrict__ xpos,
            u16* __restrict__ xneg) {
  __shared__ __align__(16) unsigned char sm[40960];
  const int lane = threadIdx.x & 63, wl = threadIdx.x >> 6;
  const int g = lane >> 4, li = lane & 15;

  const int s = blockIdx.x;            // 0..639
  const int xcd = s & 7, j = s >> 3;
  const int hh = 2 * xcd + (j & 1);
  const int u = j >> 1;                // 0..39
  const bool shared_blk = (u < 32);
  const int qb = shared_blk ? u : (32 + ((u - 32) >> 1));
  const int mode = shared_blk ? 0 : ((u - 32) & 1);
  const int q0 = qb * 64 + wl * 16;

  const u16* khh = kh + (size_t)hh * NSEQ * 128;
  const u16* vTh = vT + (size_t)hh * 128 * NSEQ;
  unsigned char* pb = sm + 32768 + wl * 2048;

  s8x aq[4];
  {
    int ql = q0 + li;
    int qp = (mode && ql >= 2048) ? ql + 256 : ql;
    const u16* base = qh + ((size_t)hh * NSEQ + qp) * 128 + g * 8;
#pragma unroll
    for (int ds = 0; ds < 4; ++ds) aq[ds] = *(const s8x*)(base + ds * 32);
  }

  const f4x zf = {0.f, 0.f, 0.f, 0.f};
  f4x o1[9];
  float m1[4];
#pragma unroll
  for (int dt = 0; dt < 9; ++dt) o1[dt] = zf;
#pragma unroll
  for (int r = 0; r < 4; ++r) m1[r] = -1e30f;

  const int n1 = shared_blk ? 32 : 36;
  for (int t = 0; t < n1; ++t) {
    int kphys = (mode && t >= 32) ? 2304 + (t - 32) * 64 : t * 64;
    stage_kv(khh, vTh, kphys, sm, lane, wl);
    __syncthreads();
    tile_compute(sm, pb, aq, g, li, o1, m1);
    __syncthreads();
  }

  if (shared_blk) {
    f4x o2[9];
    float m2[4];
#pragma unroll
    for (int dt = 0; dt < 9; ++dt) o2[dt] = o1[dt];
#pragma unroll
    for (int r = 0; r < 4; ++r) m2[r] = m1[r];
    for (int t = 0; t < 4; ++t) {              // pos tail: phys 2048..2303
      stage_kv(khh, vTh, 2048 + t * 64, sm, lane, wl);
      __syncthreads();
      tile_compute(sm, pb, aq, g, li, o1, m1);
      __syncthreads();
    }
    epilogue(xpos, q0, hh, g, li, o1);         // free o1 before neg tail
    for (int t = 0; t < 4; ++t) {              // neg tail: phys 2304..2559
      stage_kv(khh, vTh, 2304 + t * 64, sm, lane, wl);
      __syncthreads();
      tile_compute(sm, pb, aq, g, li, o2, m2);
      __syncthreads();
    }
    epilogue(xneg, q0, hh, g, li, o2);
  } else {
    epilogue(mode ? xneg : xpos, q0, hh, g, li, o1);
  }
}

// ---- NAG combine (bf16 in) + tail copy, bf16 X out --------------------------
__global__ void k_nag(const u16* __restrict__ xp, const u16* __restrict__ xn,
                      u16* __restrict__ X) {
  int n = blockIdx.x, t = threadIdx.x;
  if (n >= NSDPA) {   // rows 2304..2559 = x_neg rows 2048..2303 (raw copy)
    *(uint4*)(X + (size_t)n * NDIM + t * 8) =
        *(const uint4*)(xn + (size_t)(n - 256) * NDIM + t * 8);
    return;
  }
  uint4 up = *(const uint4*)(xp + (size_t)n * NDIM + t * 8);
  uint4 un = *(const uint4*)(xn + (size_t)n * NDIM + t * 8);
  unsigned wp[4] = {up.x, up.y, up.z, up.w};
  unsigned wn[4] = {un.x, un.y, un.z, un.w};
  float pv[8], nv[8], gv[8];
#pragma unroll
  for (int i = 0; i < 4; ++i) {
    pv[2 * i] = bf2f(wp[i] << 16);  pv[2 * i + 1] = bf2f(wp[i] & 0xFFFF0000u);
    nv[2 * i] = bf2f(wn[i] << 16);  nv[2 * i + 1] = bf2f(wn[i] & 0xFFFF0000u);
  }
  float sp = 0.f, sg = 0.f;
#pragma unroll
  for (int i = 0; i < 8; ++i) {
    float gq = 5.f * pv[i] - 4.f * nv[i];
    gv[i] = gq; sp += fabsf(pv[i]); sg += fabsf(gq);
  }
#pragma unroll
  for (int m = 32; m >= 1; m >>= 1) { sp += __shfl_xor(sp, m); sg += __shfl_xor(sg, m); }
  __shared__ float red[2][4];
  int wid = t >> 6, lane = t & 63;
  if (lane == 0) { red[0][wid] = sp; red[1][wid] = sg; }
  __syncthreads();
  float np_ = red[0][0] + red[0][1] + red[0][2] + red[0][3];
  float ng_ = red[1][0] + red[1][1] + red[1][2] + red[1][3];
  float ratio = ng_ / np_;
  if (isnan(ratio)) ratio = 10.f;
  float factor = np_ * 2.5f / (ng_ + 1e-7f);
  float mul = (ratio > 2.5f) ? factor : 1.f;
  uint4 p;
  u16 ob[8];
#pragma unroll
  for (int i = 0; i < 8; ++i) ob[i] = f2bf(gv[i] * mul * 0.25f + pv[i] * 0.75f);
  p.x = (unsigned)ob[0] | ((unsigned)ob[1] << 16);
  p.y = (unsigned)ob[2] | ((unsigned)ob[3] << 16);
  p.z = (unsigned)ob[4] | ((unsigned)ob[5] << 16);
  p.w = (unsigned)ob[6] | ((unsigned)ob[7] << 16);
  *(uint4*)(X + (size_t)n * NDIM + t * 8) = p;
}

// ---------------------------------------------------------------------------
extern "C" void kernel_launch(void* const* d_in, const int* in_sizes, int n_in,
                              void* d_out, int out_size, void* d_ws, size_t ws_size,
                              hipStream_t stream) {
  const float* h   = (const float*)d_in[0];
  const float* wq  = (const float*)d_in[1];
  const float* wk  = (const float*)d_in[2];
  const float* wv  = (const float*)d_in[3];
  const float* wo  = (const float*)d_in[4];
  const float* nqw = (const float*)d_in[5];
  const float* nkw = (const float*)d_in[6];
  const float* fc  = (const float*)d_in[7];
  (void)in_sizes; (void)n_in; (void)out_size; (void)ws_size;

  char* ws = (char*)d_ws;
  u16*   wB   = (u16*)ws;                                   // 4 * 2048*2048 bf16 (33.55 MB)
  u16*   hB   = (u16*)(ws + 33554432);                      // 2560*2048 bf16; later X
  u16*   qkvb = (u16*)(ws + 44040192);                      // 2560*6144 bf16 (31.5 MB)
  u16*   qh   = (u16*)(ws + 106954752);                     // 16*2560*128 bf16
  u16*   kh   = qh + (size_t)16 * 2560 * 128;
  u16*   vT   = kh + (size_t)16 * 2560 * 128;
  u16*   xpos = (u16*)(ws + 44040192);                      // alias (qkvb dead after k_prep)
  u16*   xneg = xpos + (size_t)NSDPA * NDIM;
  u16*   X    = hB;                                         // alias (hB dead after GEMM1)

  static bool attr_done = false;
  if (!attr_done) {
    hipFuncSetAttribute((const void*)k_gemm256,
                        hipFuncAttributeMaxDynamicSharedMemorySize, 131072);
    attr_done = true;
  }

  k_cast<<<10752, 256, 0, stream>>>(h, wq, wk, wv, wo, hB, wB);
  k_gemm256<<<240, 512, 131072, stream>>>(hB, wB, qkvb, 2048, 6144, 24);
  k_prep<<<10880, 256, 0, stream>>>(qkvb, nqw, nkw, fc, qh, kh, vT);
  k_attn<<<640, 256, 0, stream>>>(qh, kh, vT, xpos, xneg);
  k_nag<<<2560, 256, 0, stream>>>(xpos, xneg, X);
  k_gemm_bt<<<320, 256, 0, stream>>>(X, wB + 12582912, (float*)d_out, 2048, 2048, 16);
}

// Round 12
// 246.765 us; speedup vs baseline: 1.2940x; 1.2940x over previous
//
#include <hip/hip_runtime.h>
#include <stdint.h>

// ---------------------------------------------------------------------------
// Attention_53790170415368 : NAG dual-SDPA attention block, MI355X / gfx950
// R12: revert k_attn to __launch_bounds__(256,3) (R11's (256,4) capped VGPRs
//      at 64 -> spill storm, 112->188us). Keep GEMM2 XCD swizzle from R11.
//      Identical to R10 otherwise.
// ---------------------------------------------------------------------------

typedef short s8x __attribute__((ext_vector_type(8)));   // 8 x bf16 (raw bits)
typedef float f4x __attribute__((ext_vector_type(4)));
typedef unsigned short u16;

#define NDIM   2048
#define NHEAD  16
#define NHD    128
#define NSEQ   2560
#define NSDPA  2304

__device__ __forceinline__ u16 f2bf(float f) {
  union { float f; unsigned u; } v; v.f = f;
  unsigned r = v.u + 0x7FFFu + ((v.u >> 16) & 1u);   // RNE
  return (u16)(r >> 16);
}

__device__ __forceinline__ float bf2f(unsigned hi16_in_place) {
  union { unsigned u; float f; } v; v.u = hi16_in_place;
  return v.f;
}

__device__ __forceinline__ void gload16(const void* g, void* l) {
  __builtin_amdgcn_global_load_lds(
      (const __attribute__((address_space(1))) unsigned*)g,
      (__attribute__((address_space(3))) unsigned*)l, 16, 0, 0);
}

// ---- merged fp32 -> bf16 casts: h (2560 blks) + 4 weights (4x2048 blks) -----
__global__ void k_cast(const float* __restrict__ h, const float* __restrict__ w0,
                       const float* __restrict__ w1, const float* __restrict__ w2,
                       const float* __restrict__ w3, u16* __restrict__ hB,
                       u16* __restrict__ wB) {
  int bid = blockIdx.x;
  const float* src; u16* dst; int i;
  if (bid < 2560) {                       // h: 655360 groups of 8
    src = h; dst = hB; i = bid * 256 + threadIdx.x;
  } else {
    int b = bid - 2560;
    int m = b >> 11;                      // /2048
    i = (b & 2047) * 256 + threadIdx.x;   // 0..524287
    src = (m == 0) ? w0 : (m == 1) ? w1 : (m == 2) ? w2 : w3;
    dst = wB + (size_t)m * 4194304;
  }
  const float4* s4 = (const float4*)src + (size_t)i * 2;
  float4 a = s4[0], b4 = s4[1];
  uint4 p;
  p.x = (unsigned)f2bf(a.x) | ((unsigned)f2bf(a.y) << 16);
  p.y = (unsigned)f2bf(a.z) | ((unsigned)f2bf(a.w) << 16);
  p.z = (unsigned)f2bf(b4.x) | ((unsigned)f2bf(b4.y) << 16);
  p.w = (unsigned)f2bf(b4.z) | ((unsigned)f2bf(b4.w) << 16);
  *(uint4*)(dst + (size_t)i * 8) = p;
}

// ---- C[M,N] f32 = A[M,K]bf16 @ B[N,K]bf16^T  (m97, 128x128, XCD swizzle) ----
__global__ __launch_bounds__(256, 2)
void k_gemm_bt(const u16* __restrict__ A, const u16* __restrict__ B,
               float* __restrict__ C, int K, int ldc, int nbn) {
  __shared__ __align__(16) unsigned char sm[16384];  // A tile 8K | B tile 8K
  const int cpx = gridDim.x >> 3;
  const int f = blockIdx.x;
  const int swz = (f & 7) * cpx + (f >> 3);          // bijective: grid % 8 == 0
  const int bm = (swz / nbn) * 128, bn = (swz % nbn) * 128;
  const int lane = threadIdx.x & 63, wl = threadIdx.x >> 6;
  const int wm = wl >> 1, wn = wl & 1;
  const int g = lane >> 4, li = lane & 15;
  f4x acc[4][4] = {};
  const int nk = K >> 5;
  for (int kk = 0; kk < nk; ++kk) {
#pragma unroll
    for (int c = 0; c < 2; ++c) {
      int base = (wl * 2 + c) * 1024;
      int row = (base >> 6) + (lane >> 2);
      int colb = (lane & 3) * 16;
      gload16((const char*)A + ((size_t)(bm + row) * K + kk * 32) * 2 + colb, sm + base);
      gload16((const char*)B + ((size_t)(bn + row) * K + kk * 32) * 2 + colb, sm + 8192 + base);
    }
    __syncthreads();
    s8x a[4];
#pragma unroll
    for (int mt = 0; mt < 4; ++mt)
      a[mt] = *(const s8x*)(sm + (wm * 64 + mt * 16 + li) * 64 + g * 16);
#pragma unroll
    for (int nt = 0; nt < 4; ++nt) {
      s8x b = *(const s8x*)(sm + 8192 + (wn * 64 + nt * 16 + li) * 64 + g * 16);
#pragma unroll
      for (int mt = 0; mt < 4; ++mt)
        acc[mt][nt] = __builtin_amdgcn_mfma_f32_16x16x32_bf16(a[mt], b, acc[mt][nt], 0, 0, 0);
    }
    __syncthreads();
  }
#pragma unroll
  for (int mt = 0; mt < 4; ++mt)
#pragma unroll
    for (int nt = 0; nt < 4; ++nt)
#pragma unroll
      for (int r = 0; r < 4; ++r) {
        int row = bm + wm * 64 + mt * 16 + g * 4 + r;
        int col = bn + wn * 64 + nt * 16 + li;
        C[(size_t)row * ldc + col] = acc[mt][nt][r];
      }
}

// ---- 256x256 tile, BK=64, 8 waves (2Mx4N), 128KB LDS dbuf, 4-phase/tile -----
// Writes bf16 output. LDS slot (64KB): A [256][64]bf16 swz @0, B @32KB.
__device__ __forceinline__ void stageAB256(const u16* __restrict__ M, int K,
                                           int row0, int kk, unsigned char* dst,
                                           int tid) {
#pragma unroll
  for (int c = 0; c < 4; ++c) {
    int idx = c * 512 + tid;                 // chunk 0..2047 (row r, chunk idx&7)
    int r = idx >> 3, cc = idx & 7;
    gload16(M + (size_t)(row0 + r) * K + kk + ((cc ^ (r & 7)) * 8), dst + idx * 16);
  }
}

#define G256_SYNC() do { __builtin_amdgcn_s_barrier();                        \
    asm volatile("s_waitcnt lgkmcnt(0)" ::: "memory");                        \
    __builtin_amdgcn_sched_barrier(0); } while (0)

__global__ __launch_bounds__(512, 2)
void k_gemm256(const u16* __restrict__ A, const u16* __restrict__ B,
               u16* __restrict__ C, int K, int ldc, int nbn) {
  extern __shared__ __align__(16) unsigned char sm[];     // 131072
  const int tid = threadIdx.x;
  const int lane = tid & 63, wid = tid >> 6;
  const int g = lane >> 4, li = lane & 15;
  const int wr = wid >> 2, wc = wid & 3;

  const int cpx = gridDim.x >> 3;
  const int f = blockIdx.x;
  const int swz = (f & 7) * cpx + (f >> 3);
  const int bm = (swz / nbn) * 256, bn = (swz % nbn) * 256;

  f4x acc[8][4] = {};
  const int nk = K >> 6;

  stageAB256(A, K, bm, 0, sm, tid);
  stageAB256(B, K, bn, 0, sm + 32768, tid);
  stageAB256(A, K, bm, 64, sm + 65536, tid);
  stageAB256(B, K, bn, 64, sm + 98304, tid);
  asm volatile("s_waitcnt vmcnt(8)" ::: "memory");
  __builtin_amdgcn_s_barrier();

  for (int t = 0; t < nk; ++t) {
    unsigned char* sA = sm + (t & 1) * 65536;
    unsigned char* sB = sA + 32768;
    s8x a[8][2], b[4][2];

#pragma unroll
    for (int mt = 0; mt < 4; ++mt) {
      int r = wr * 128 + mt * 16 + li;
#pragma unroll
      for (int ks = 0; ks < 2; ++ks)
        a[mt][ks] = *(const s8x*)(sA + r * 128 + (((ks * 4 + g) ^ (r & 7)) * 16));
    }
#pragma unroll
    for (int nt = 0; nt < 4; ++nt) {
      int r = wc * 64 + nt * 16 + li;
      b[nt][0] = *(const s8x*)(sB + r * 128 + ((g ^ (r & 7)) * 16));
    }
    G256_SYNC();
    __builtin_amdgcn_s_setprio(1);
#pragma unroll
    for (int nt = 0; nt < 4; ++nt)
#pragma unroll
      for (int mt = 0; mt < 4; ++mt)
        acc[mt][nt] = __builtin_amdgcn_mfma_f32_16x16x32_bf16(a[mt][0], b[nt][0], acc[mt][nt], 0, 0, 0);
    __builtin_amdgcn_s_setprio(0);
    __builtin_amdgcn_s_barrier();

#pragma unroll
    for (int mt = 4; mt < 8; ++mt) {
      int r = wr * 128 + mt * 16 + li;
#pragma unroll
      for (int ks = 0; ks < 2; ++ks)
        a[mt][ks] = *(const s8x*)(sA + r * 128 + (((ks * 4 + g) ^ (r & 7)) * 16));
    }
#pragma unroll
    for (int nt = 0; nt < 4; ++nt) {
      int r = wc * 64 + nt * 16 + li;
      b[nt][1] = *(const s8x*)(sB + r * 128 + (((4 + g) ^ (r & 7)) * 16));
    }
    G256_SYNC();
    __builtin_amdgcn_s_setprio(1);
#pragma unroll
    for (int nt = 0; nt < 4; ++nt)
#pragma unroll
      for (int mt = 4; mt < 8; ++mt)
        acc[mt][nt] = __builtin_amdgcn_mfma_f32_16x16x32_bf16(a[mt][0], b[nt][0], acc[mt][nt], 0, 0, 0);
    __builtin_amdgcn_s_setprio(0);
    __builtin_amdgcn_s_barrier();

    if (t + 2 < nk) stageAB256(A, K, bm, (t + 2) * 64, sA, tid);
    G256_SYNC();
    __builtin_amdgcn_s_setprio(1);
#pragma unroll
    for (int nt = 0; nt < 4; ++nt)
#pragma unroll
      for (int mt = 0; mt < 4; ++mt)
        acc[mt][nt] = __builtin_amdgcn_mfma_f32_16x16x32_bf16(a[mt][1], b[nt][1], acc[mt][nt], 0, 0, 0);
    __builtin_amdgcn_s_setprio(0);
    __builtin_amdgcn_s_barrier();

    if (t + 2 < nk) stageAB256(B, K, bn, (t + 2) * 64, sB, tid);
    G256_SYNC();
    __builtin_amdgcn_s_setprio(1);
#pragma unroll
    for (int nt = 0; nt < 4; ++nt)
#pragma unroll
      for (int mt = 4; mt < 8; ++mt)
        acc[mt][nt] = __builtin_amdgcn_mfma_f32_16x16x32_bf16(a[mt][1], b[nt][1], acc[mt][nt], 0, 0, 0);
    __builtin_amdgcn_s_setprio(0);
    if (t + 1 < nk) {
      if (t + 2 < nk) asm volatile("s_waitcnt vmcnt(8)" ::: "memory");
      else            asm volatile("s_waitcnt vmcnt(0)" ::: "memory");
      __builtin_amdgcn_s_barrier();
    }
  }

#pragma unroll
  for (int mt = 0; mt < 8; ++mt)
#pragma unroll
    for (int nt = 0; nt < 4; ++nt)
#pragma unroll
      for (int rr = 0; rr < 4; ++rr) {
        int row = bm + wr * 128 + mt * 16 + g * 4 + rr;
        int col = bn + wc * 64 + nt * 16 + li;
        C[(size_t)row * ldc + col] = f2bf(acc[mt][nt][rr]);
      }
}

// ---- merged prep: rmsnorm+rope (blocks <10240) | v-transpose (blocks >=10240)
__global__ void k_prep(const u16* __restrict__ qkv, const float* __restrict__ nqw,
                       const float* __restrict__ nkw, const float* __restrict__ fc,
                       u16* __restrict__ qh, u16* __restrict__ kh,
                       u16* __restrict__ vT) {
  __shared__ u16 t[128][65];
  int bid = blockIdx.x;
  if (bid < 10240) {
    int wid = threadIdx.x >> 6, lane = threadIdx.x & 63;
    int pair = bid * 4 + wid;               // 0 .. 40959
    int s = pair >> 4, hh = pair & 15;
    const u16* qrow = qkv + (size_t)s * 6144 + hh * 128;
    unsigned uq = *(const unsigned*)(qrow + lane * 2);
    unsigned uk = *(const unsigned*)(qrow + 2048 + lane * 2);
    float qx = bf2f(uq << 16), qy = bf2f(uq & 0xFFFF0000u);
    float kx = bf2f(uk << 16), ky = bf2f(uk & 0xFFFF0000u);
    float sq = qx * qx + qy * qy;
    float sk = kx * kx + ky * ky;
#pragma unroll
    for (int m = 32; m >= 1; m >>= 1) { sq += __shfl_xor(sq, m); sk += __shfl_xor(sk, m); }
    float rq = rsqrtf(sq * (1.f / 128.f) + 1e-5f);
    float rk = rsqrtf(sk * (1.f / 128.f) + 1e-5f);
    float2 wq2 = *(const float2*)(nqw + lane * 2);
    float2 wk2 = *(const float2*)(nkw + lane * 2);
    float2 cs = *(const float2*)(fc + (size_t)s * 128 + lane * 2);
    float q0 = qx * rq * wq2.x, q1 = qy * rq * wq2.y;
    float k0 = kx * rk * wk2.x, k1 = ky * rk * wk2.y;
    unsigned qo = (unsigned)f2bf(q0 * cs.x - q1 * cs.y) | ((unsigned)f2bf(q1 * cs.x + q0 * cs.y) << 16);
    unsigned ko = (unsigned)f2bf(k0 * cs.x - k1 * cs.y) | ((unsigned)f2bf(k1 * cs.x + k0 * cs.y) << 16);
    *(unsigned*)(qh + ((size_t)hh * NSEQ + s) * 128 + lane * 2) = qo;
    *(unsigned*)(kh + ((size_t)hh * NSEQ + s) * 128 + lane * 2) = ko;
    return;
  }
  int bx = bid - 10240;                      // 0..639: 40 s-blocks x 16 heads
  int s0 = (bx % 40) * 64, hh = bx / 40;
  int tid = threadIdx.x;
#pragma unroll
  for (int rep = 0; rep < 16; ++rep) {
    int idx = rep * 256 + tid;               // (row sr, u32-pair d2)
    int sr = idx >> 6, d2 = idx & 63;
    unsigned v2 = *(const unsigned*)(qkv + (size_t)(s0 + sr) * 6144 + 4096 + hh * 128 + d2 * 2);
    t[d2 * 2][sr] = (u16)v2;
    t[d2 * 2 + 1][sr] = (u16)(v2 >> 16);
  }
  __syncthreads();
#pragma unroll
  for (int rep = 0; rep < 16; ++rep) {
    int idx = rep * 256 + tid; int d = idx >> 5, sc2 = (idx & 31) * 2;
    unsigned val = (unsigned)t[d][sc2] | ((unsigned)t[d][sc2 + 1] << 16);
    *(unsigned*)(vT + ((size_t)hh * 128 + d) * NSEQ + s0 + sc2) = val;
  }
}

// ---- flash attention helpers ------------------------------------------------
// LDS (40960 B): K [64][128]swz @0 (16K) | vT [128][64]swz @16K (16K) | P @32K
__device__ __forceinline__ void stage_kv(const u16* __restrict__ khh,
                                         const u16* __restrict__ vTh,
                                         int kphys, unsigned char* sm,
                                         int lane, int wl) {
#pragma unroll
  for (int c = 0; c < 4; ++c) {
    int base = (wl * 4 + c) * 1024;
    { int row = (base >> 8) + (lane >> 4);                 // K tile: 64 rows x 256B
      int src = ((lane & 15) * 16) ^ ((row & 7) << 4);
      gload16((const char*)(khh + (size_t)(kphys + row) * 128) + src, sm + base); }
    { int row = (base >> 7) + (lane >> 3);                 // vT tile: 128 rows x 128B
      int src = ((lane & 7) * 16) ^ ((row & 7) << 4);
      gload16((const char*)(vTh + (size_t)row * NSEQ + kphys) + src, sm + 16384 + base); }
  }
}

// o[0..7] = output d-columns, o[8] = softmax denominator (MFMA-of-ones column).
__device__ __forceinline__ void tile_compute(unsigned char* sm, unsigned char* pb,
                                             const s8x (&aq)[4], int g, int li,
                                             f4x (&o)[9], float (&mold)[4]) {
  const float S2 = 0.08838834764831845f * 1.4426950408889634f;  // scale*log2(e)
  const float THR_RAW = 90.0f;                 // ~8 in exp-arg units
  const s8x PONE = {16256, 16256, 16256, 16256, 16256, 16256, 16256, 16256}; // bf16 1.0
  const f4x zf = {0.f, 0.f, 0.f, 0.f};
  f4x sc[4];
#pragma unroll
  for (int nt = 0; nt < 4; ++nt) sc[nt] = zf;
  __builtin_amdgcn_s_setprio(1);
#pragma unroll
  for (int nt = 0; nt < 4; ++nt) {
    int row = nt * 16 + li;
    int rx = (row & 7) << 4;
#pragma unroll
    for (int ds = 0; ds < 4; ++ds) {
      s8x bk = *(const s8x*)(sm + row * 256 + ((ds * 64 + g * 16) ^ rx));
      sc[nt] = __builtin_amdgcn_mfma_f32_16x16x32_bf16(aq[ds], bk, sc[nt], 0, 0, 0);
    }
  }
  __builtin_amdgcn_s_setprio(0);

  float tl[4];
#pragma unroll
  for (int r = 0; r < 4; ++r)
    tl[r] = fmaxf(fmaxf(sc[0][r], sc[1][r]), fmaxf(sc[2][r], sc[3][r]));
  bool need = (tl[0] > mold[0] + THR_RAW) || (tl[1] > mold[1] + THR_RAW) ||
              (tl[2] > mold[2] + THR_RAW) || (tl[3] > mold[3] + THR_RAW);
  if (__any((int)need)) {
#pragma unroll
    for (int r = 0; r < 4; ++r) {
      float t = tl[r];
#pragma unroll
      for (int msk = 8; msk >= 1; msk >>= 1) t = fmaxf(t, __shfl_xor(t, msk));
      float mn = fmaxf(mold[r], t);
      float corr = exp2f((mold[r] - mn) * S2);
      mold[r] = mn;
#pragma unroll
      for (int dt = 0; dt < 9; ++dt) o[dt][r] *= corr;
    }
  }
  float nb[4];
#pragma unroll
  for (int r = 0; r < 4; ++r) nb[r] = -mold[r] * S2;
#pragma unroll
  for (int nt = 0; nt < 4; ++nt) {             // P A-layout [16 q][64 key] swz
    int colb = (nt * 16 + li) * 2;
#pragma unroll
    for (int r = 0; r < 4; ++r) {
      float p = exp2f(fmaf(sc[nt][r], S2, nb[r]));
      union { float f; unsigned u; } pv_; pv_.f = p;
      int q = g * 4 + r;
      *(u16*)(pb + q * 128 + (colb ^ ((q & 7) << 4))) = (u16)(pv_.u >> 16);
    }
  }
  __builtin_amdgcn_s_setprio(1);
#pragma unroll
  for (int ks = 0; ks < 2; ++ks) {
    s8x pa = *(const s8x*)(pb + li * 128 + ((ks * 64 + g * 16) ^ ((li & 7) << 4)));
#pragma unroll
    for (int dt = 0; dt < 8; ++dt) {
      int row = dt * 16 + li;
      s8x bv = *(const s8x*)(sm + 16384 + row * 128 + ((ks * 64 + g * 16) ^ ((row & 7) << 4)));
      o[dt] = __builtin_amdgcn_mfma_f32_16x16x32_bf16(pa, bv, o[dt], 0, 0, 0);
    }
    o[8] = __builtin_amdgcn_mfma_f32_16x16x32_bf16(pa, PONE, o[8], 0, 0, 0);
  }
  __builtin_amdgcn_s_setprio(0);
}

__device__ __forceinline__ void epilogue(u16* __restrict__ out, int q0, int hh,
                                         int g, int li, const f4x (&o)[9]) {
  float inv[4];
#pragma unroll
  for (int r = 0; r < 4; ++r) inv[r] = 1.f / o[8][r];
#pragma unroll
  for (int dt = 0; dt < 8; ++dt)
#pragma unroll
    for (int r = 0; r < 4; ++r) {
      int n = q0 + g * 4 + r;
      int col = hh * 128 + dt * 16 + li;
      out[(size_t)n * NDIM + col] = f2bf(o[dt][r] * inv[r]);
    }
}

// ---- fused pos/neg flash attention ------------------------------------------
// 640 blocks, 256 thr (4 waves), 64 q-rows/WG (16/wave). XCD x: heads {2x,2x+1}.
__global__ __launch_bounds__(256, 3)
void k_attn(const u16* __restrict__ qh, const u16* __restrict__ kh,
            const u16* __restrict__ vT, u16* __restrict__ xpos,
            u16* __restrict__ xneg) {
  __shared__ __align__(16) unsigned char sm[40960];
  const int lane = threadIdx.x & 63, wl = threadIdx.x >> 6;
  const int g = lane >> 4, li = lane & 15;

  const int s = blockIdx.x;            // 0..639
  const int xcd = s & 7, j = s >> 3;
  const int hh = 2 * xcd + (j & 1);
  const int u = j >> 1;                // 0..39
  const bool shared_blk = (u < 32);
  const int qb = shared_blk ? u : (32 + ((u - 32) >> 1));
  const int mode = shared_blk ? 0 : ((u - 32) & 1);
  const int q0 = qb * 64 + wl * 16;

  const u16* khh = kh + (size_t)hh * NSEQ * 128;
  const u16* vTh = vT + (size_t)hh * 128 * NSEQ;
  unsigned char* pb = sm + 32768 + wl * 2048;

  s8x aq[4];
  {
    int ql = q0 + li;
    int qp = (mode && ql >= 2048) ? ql + 256 : ql;
    const u16* base = qh + ((size_t)hh * NSEQ + qp) * 128 + g * 8;
#pragma unroll
    for (int ds = 0; ds < 4; ++ds) aq[ds] = *(const s8x*)(base + ds * 32);
  }

  const f4x zf = {0.f, 0.f, 0.f, 0.f};
  f4x o1[9];
  float m1[4];
#pragma unroll
  for (int dt = 0; dt < 9; ++dt) o1[dt] = zf;
#pragma unroll
  for (int r = 0; r < 4; ++r) m1[r] = -1e30f;

  const int n1 = shared_blk ? 32 : 36;
  for (int t = 0; t < n1; ++t) {
    int kphys = (mode && t >= 32) ? 2304 + (t - 32) * 64 : t * 64;
    stage_kv(khh, vTh, kphys, sm, lane, wl);
    __syncthreads();
    tile_compute(sm, pb, aq, g, li, o1, m1);
    __syncthreads();
  }

  if (shared_blk) {
    f4x o2[9];
    float m2[4];
#pragma unroll
    for (int dt = 0; dt < 9; ++dt) o2[dt] = o1[dt];
#pragma unroll
    for (int r = 0; r < 4; ++r) m2[r] = m1[r];
    for (int t = 0; t < 4; ++t) {              // pos tail: phys 2048..2303
      stage_kv(khh, vTh, 2048 + t * 64, sm, lane, wl);
      __syncthreads();
      tile_compute(sm, pb, aq, g, li, o1, m1);
      __syncthreads();
    }
    epilogue(xpos, q0, hh, g, li, o1);         // free o1 before neg tail
    for (int t = 0; t < 4; ++t) {              // neg tail: phys 2304..2559
      stage_kv(khh, vTh, 2304 + t * 64, sm, lane, wl);
      __syncthreads();
      tile_compute(sm, pb, aq, g, li, o2, m2);
      __syncthreads();
    }
    epilogue(xneg, q0, hh, g, li, o2);
  } else {
    epilogue(mode ? xneg : xpos, q0, hh, g, li, o1);
  }
}

// ---- NAG combine (bf16 in) + tail copy, bf16 X out --------------------------
__global__ void k_nag(const u16* __restrict__ xp, const u16* __restrict__ xn,
                      u16* __restrict__ X) {
  int n = blockIdx.x, t = threadIdx.x;
  if (n >= NSDPA) {   // rows 2304..2559 = x_neg rows 2048..2303 (raw copy)
    *(uint4*)(X + (size_t)n * NDIM + t * 8) =
        *(const uint4*)(xn + (size_t)(n - 256) * NDIM + t * 8);
    return;
  }
  uint4 up = *(const uint4*)(xp + (size_t)n * NDIM + t * 8);
  uint4 un = *(const uint4*)(xn + (size_t)n * NDIM + t * 8);
  unsigned wp[4] = {up.x, up.y, up.z, up.w};
  unsigned wn[4] = {un.x, un.y, un.z, un.w};
  float pv[8], nv[8], gv[8];
#pragma unroll
  for (int i = 0; i < 4; ++i) {
    pv[2 * i] = bf2f(wp[i] << 16);  pv[2 * i + 1] = bf2f(wp[i] & 0xFFFF0000u);
    nv[2 * i] = bf2f(wn[i] << 16);  nv[2 * i + 1] = bf2f(wn[i] & 0xFFFF0000u);
  }
  float sp = 0.f, sg = 0.f;
#pragma unroll
  for (int i = 0; i < 8; ++i) {
    float gq = 5.f * pv[i] - 4.f * nv[i];
    gv[i] = gq; sp += fabsf(pv[i]); sg += fabsf(gq);
  }
#pragma unroll
  for (int m = 32; m >= 1; m >>= 1) { sp += __shfl_xor(sp, m); sg += __shfl_xor(sg, m); }
  __shared__ float red[2][4];
  int wid = t >> 6, lane = t & 63;
  if (lane == 0) { red[0][wid] = sp; red[1][wid] = sg; }
  __syncthreads();
  float np_ = red[0][0] + red[0][1] + red[0][2] + red[0][3];
  float ng_ = red[1][0] + red[1][1] + red[1][2] + red[1][3];
  float ratio = ng_ / np_;
  if (isnan(ratio)) ratio = 10.f;
  float factor = np_ * 2.5f / (ng_ + 1e-7f);
  float mul = (ratio > 2.5f) ? factor : 1.f;
  uint4 p;
  u16 ob[8];
#pragma unroll
  for (int i = 0; i < 8; ++i) ob[i] = f2bf(gv[i] * mul * 0.25f + pv[i] * 0.75f);
  p.x = (unsigned)ob[0] | ((unsigned)ob[1] << 16);
  p.y = (unsigned)ob[2] | ((unsigned)ob[3] << 16);
  p.z = (unsigned)ob[4] | ((unsigned)ob[5] << 16);
  p.w = (unsigned)ob[6] | ((unsigned)ob[7] << 16);
  *(uint4*)(X + (size_t)n * NDIM + t * 8) = p;
}

// ---------------------------------------------------------------------------
extern "C" void kernel_launch(void* const* d_in, const int* in_sizes, int n_in,
                              void* d_out, int out_size, void* d_ws, size_t ws_size,
                              hipStream_t stream) {
  const float* h   = (const float*)d_in[0];
  const float* wq  = (const float*)d_in[1];
  const float* wk  = (const float*)d_in[2];
  const float* wv  = (const float*)d_in[3];
  const float* wo  = (const float*)d_in[4];
  const float* nqw = (const float*)d_in[5];
  const float* nkw = (const float*)d_in[6];
  const float* fc  = (const float*)d_in[7];
  (void)in_sizes; (void)n_in; (void)out_size; (void)ws_size;

  char* ws = (char*)d_ws;
  u16*   wB   = (u16*)ws;                                   // 4 * 2048*2048 bf16 (33.55 MB)
  u16*   hB   = (u16*)(ws + 33554432);                      // 2560*2048 bf16; later X
  u16*   qkvb = (u16*)(ws + 44040192);                      // 2560*6144 bf16 (31.5 MB)
  u16*   qh   = (u16*)(ws + 106954752);                     // 16*2560*128 bf16
  u16*   kh   = qh + (size_t)16 * 2560 * 128;
  u16*   vT   = kh + (size_t)16 * 2560 * 128;
  u16*   xpos = (u16*)(ws + 44040192);                      // alias (qkvb dead after k_prep)
  u16*   xneg = xpos + (size_t)NSDPA * NDIM;
  u16*   X    = hB;                                         // alias (hB dead after GEMM1)

  static bool attr_done = false;
  if (!attr_done) {
    hipFuncSetAttribute((const void*)k_gemm256,
                        hipFuncAttributeMaxDynamicSharedMemorySize, 131072);
    attr_done = true;
  }

  k_cast<<<10752, 256, 0, stream>>>(h, wq, wk, wv, wo, hB, wB);
  k_gemm256<<<240, 512, 131072, stream>>>(hB, wB, qkvb, 2048, 6144, 24);
  k_prep<<<10880, 256, 0, stream>>>(qkvb, nqw, nkw, fc, qh, kh, vT);
  k_attn<<<640, 256, 0, stream>>>(qh, kh, vT, xpos, xneg);
  k_nag<<<2560, 256, 0, stream>>>(xpos, xneg, X);
  k_gemm_bt<<<320, 256, 0, stream>>>(X, wB + 12582912, (float*)d_out, 2048, 2048, 16);
}

// Round 13
// 242.061 us; speedup vs baseline: 1.3191x; 1.0194x over previous
//
#include <hip/hip_runtime.h>
#include <stdint.h>

// ---------------------------------------------------------------------------
// Attention_53790170415368 : NAG dual-SDPA attention block, MI355X / gfx950
// R13: swapped-QK^T in k_attn (mfma(K,Q)) -> P C-layout [key][q=lane]; P-pack
//      becomes 4x ds_write_b64/lane (was 16 scattered u16, ~8-way conflicts);
//      softmax max = in-lane 15-fmax + 2 shfl_xor; mold is per-lane scalar.
//      Arithmetic value-identical to R12 (absmax fingerprint 0.001464844).
// ---------------------------------------------------------------------------

typedef short s8x __attribute__((ext_vector_type(8)));   // 8 x bf16 (raw bits)
typedef float f4x __attribute__((ext_vector_type(4)));
typedef unsigned short u16;

#define NDIM   2048
#define NHEAD  16
#define NHD    128
#define NSEQ   2560
#define NSDPA  2304

__device__ __forceinline__ u16 f2bf(float f) {
  union { float f; unsigned u; } v; v.f = f;
  unsigned r = v.u + 0x7FFFu + ((v.u >> 16) & 1u);   // RNE
  return (u16)(r >> 16);
}

__device__ __forceinline__ float bf2f(unsigned hi16_in_place) {
  union { unsigned u; float f; } v; v.u = hi16_in_place;
  return v.f;
}

__device__ __forceinline__ void gload16(const void* g, void* l) {
  __builtin_amdgcn_global_load_lds(
      (const __attribute__((address_space(1))) unsigned*)g,
      (__attribute__((address_space(3))) unsigned*)l, 16, 0, 0);
}

// ---- merged fp32 -> bf16 casts: h (2560 blks) + 4 weights (4x2048 blks) -----
__global__ void k_cast(const float* __restrict__ h, const float* __restrict__ w0,
                       const float* __restrict__ w1, const float* __restrict__ w2,
                       const float* __restrict__ w3, u16* __restrict__ hB,
                       u16* __restrict__ wB) {
  int bid = blockIdx.x;
  const float* src; u16* dst; int i;
  if (bid < 2560) {                       // h: 655360 groups of 8
    src = h; dst = hB; i = bid * 256 + threadIdx.x;
  } else {
    int b = bid - 2560;
    int m = b >> 11;                      // /2048
    i = (b & 2047) * 256 + threadIdx.x;   // 0..524287
    src = (m == 0) ? w0 : (m == 1) ? w1 : (m == 2) ? w2 : w3;
    dst = wB + (size_t)m * 4194304;
  }
  const float4* s4 = (const float4*)src + (size_t)i * 2;
  float4 a = s4[0], b4 = s4[1];
  uint4 p;
  p.x = (unsigned)f2bf(a.x) | ((unsigned)f2bf(a.y) << 16);
  p.y = (unsigned)f2bf(a.z) | ((unsigned)f2bf(a.w) << 16);
  p.z = (unsigned)f2bf(b4.x) | ((unsigned)f2bf(b4.y) << 16);
  p.w = (unsigned)f2bf(b4.z) | ((unsigned)f2bf(b4.w) << 16);
  *(uint4*)(dst + (size_t)i * 8) = p;
}

// ---- C[M,N] f32 = A[M,K]bf16 @ B[N,K]bf16^T  (m97, 128x128, XCD swizzle) ----
__global__ __launch_bounds__(256, 2)
void k_gemm_bt(const u16* __restrict__ A, const u16* __restrict__ B,
               float* __restrict__ C, int K, int ldc, int nbn) {
  __shared__ __align__(16) unsigned char sm[16384];  // A tile 8K | B tile 8K
  const int cpx = gridDim.x >> 3;
  const int f = blockIdx.x;
  const int swz = (f & 7) * cpx + (f >> 3);          // bijective: grid % 8 == 0
  const int bm = (swz / nbn) * 128, bn = (swz % nbn) * 128;
  const int lane = threadIdx.x & 63, wl = threadIdx.x >> 6;
  const int wm = wl >> 1, wn = wl & 1;
  const int g = lane >> 4, li = lane & 15;
  f4x acc[4][4] = {};
  const int nk = K >> 5;
  for (int kk = 0; kk < nk; ++kk) {
#pragma unroll
    for (int c = 0; c < 2; ++c) {
      int base = (wl * 2 + c) * 1024;
      int row = (base >> 6) + (lane >> 2);
      int colb = (lane & 3) * 16;
      gload16((const char*)A + ((size_t)(bm + row) * K + kk * 32) * 2 + colb, sm + base);
      gload16((const char*)B + ((size_t)(bn + row) * K + kk * 32) * 2 + colb, sm + 8192 + base);
    }
    __syncthreads();
    s8x a[4];
#pragma unroll
    for (int mt = 0; mt < 4; ++mt)
      a[mt] = *(const s8x*)(sm + (wm * 64 + mt * 16 + li) * 64 + g * 16);
#pragma unroll
    for (int nt = 0; nt < 4; ++nt) {
      s8x b = *(const s8x*)(sm + 8192 + (wn * 64 + nt * 16 + li) * 64 + g * 16);
#pragma unroll
      for (int mt = 0; mt < 4; ++mt)
        acc[mt][nt] = __builtin_amdgcn_mfma_f32_16x16x32_bf16(a[mt], b, acc[mt][nt], 0, 0, 0);
    }
    __syncthreads();
  }
#pragma unroll
  for (int mt = 0; mt < 4; ++mt)
#pragma unroll
    for (int nt = 0; nt < 4; ++nt)
#pragma unroll
      for (int r = 0; r < 4; ++r) {
        int row = bm + wm * 64 + mt * 16 + g * 4 + r;
        int col = bn + wn * 64 + nt * 16 + li;
        C[(size_t)row * ldc + col] = acc[mt][nt][r];
      }
}

// ---- 256x256 tile, BK=64, 8 waves (2Mx4N), 128KB LDS dbuf, 4-phase/tile -----
// Writes bf16 output. LDS slot (64KB): A [256][64]bf16 swz @0, B @32KB.
__device__ __forceinline__ void stageAB256(const u16* __restrict__ M, int K,
                                           int row0, int kk, unsigned char* dst,
                                           int tid) {
#pragma unroll
  for (int c = 0; c < 4; ++c) {
    int idx = c * 512 + tid;                 // chunk 0..2047 (row r, chunk idx&7)
    int r = idx >> 3, cc = idx & 7;
    gload16(M + (size_t)(row0 + r) * K + kk + ((cc ^ (r & 7)) * 8), dst + idx * 16);
  }
}

#define G256_SYNC() do { __builtin_amdgcn_s_barrier();                        \
    asm volatile("s_waitcnt lgkmcnt(0)" ::: "memory");                        \
    __builtin_amdgcn_sched_barrier(0); } while (0)

__global__ __launch_bounds__(512, 2)
void k_gemm256(const u16* __restrict__ A, const u16* __restrict__ B,
               u16* __restrict__ C, int K, int ldc, int nbn) {
  extern __shared__ __align__(16) unsigned char sm[];     // 131072
  const int tid = threadIdx.x;
  const int lane = tid & 63, wid = tid >> 6;
  const int g = lane >> 4, li = lane & 15;
  const int wr = wid >> 2, wc = wid & 3;

  const int cpx = gridDim.x >> 3;
  const int f = blockIdx.x;
  const int swz = (f & 7) * cpx + (f >> 3);
  const int bm = (swz / nbn) * 256, bn = (swz % nbn) * 256;

  f4x acc[8][4] = {};
  const int nk = K >> 6;

  stageAB256(A, K, bm, 0, sm, tid);
  stageAB256(B, K, bn, 0, sm + 32768, tid);
  stageAB256(A, K, bm, 64, sm + 65536, tid);
  stageAB256(B, K, bn, 64, sm + 98304, tid);
  asm volatile("s_waitcnt vmcnt(8)" ::: "memory");
  __builtin_amdgcn_s_barrier();

  for (int t = 0; t < nk; ++t) {
    unsigned char* sA = sm + (t & 1) * 65536;
    unsigned char* sB = sA + 32768;
    s8x a[8][2], b[4][2];

#pragma unroll
    for (int mt = 0; mt < 4; ++mt) {
      int r = wr * 128 + mt * 16 + li;
#pragma unroll
      for (int ks = 0; ks < 2; ++ks)
        a[mt][ks] = *(const s8x*)(sA + r * 128 + (((ks * 4 + g) ^ (r & 7)) * 16));
    }
#pragma unroll
    for (int nt = 0; nt < 4; ++nt) {
      int r = wc * 64 + nt * 16 + li;
      b[nt][0] = *(const s8x*)(sB + r * 128 + ((g ^ (r & 7)) * 16));
    }
    G256_SYNC();
    __builtin_amdgcn_s_setprio(1);
#pragma unroll
    for (int nt = 0; nt < 4; ++nt)
#pragma unroll
      for (int mt = 0; mt < 4; ++mt)
        acc[mt][nt] = __builtin_amdgcn_mfma_f32_16x16x32_bf16(a[mt][0], b[nt][0], acc[mt][nt], 0, 0, 0);
    __builtin_amdgcn_s_setprio(0);
    __builtin_amdgcn_s_barrier();

#pragma unroll
    for (int mt = 4; mt < 8; ++mt) {
      int r = wr * 128 + mt * 16 + li;
#pragma unroll
      for (int ks = 0; ks < 2; ++ks)
        a[mt][ks] = *(const s8x*)(sA + r * 128 + (((ks * 4 + g) ^ (r & 7)) * 16));
    }
#pragma unroll
    for (int nt = 0; nt < 4; ++nt) {
      int r = wc * 64 + nt * 16 + li;
      b[nt][1] = *(const s8x*)(sB + r * 128 + (((4 + g) ^ (r & 7)) * 16));
    }
    G256_SYNC();
    __builtin_amdgcn_s_setprio(1);
#pragma unroll
    for (int nt = 0; nt < 4; ++nt)
#pragma unroll
      for (int mt = 4; mt < 8; ++mt)
        acc[mt][nt] = __builtin_amdgcn_mfma_f32_16x16x32_bf16(a[mt][0], b[nt][0], acc[mt][nt], 0, 0, 0);
    __builtin_amdgcn_s_setprio(0);
    __builtin_amdgcn_s_barrier();

    if (t + 2 < nk) stageAB256(A, K, bm, (t + 2) * 64, sA, tid);
    G256_SYNC();
    __builtin_amdgcn_s_setprio(1);
#pragma unroll
    for (int nt = 0; nt < 4; ++nt)
#pragma unroll
      for (int mt = 0; mt < 4; ++mt)
        acc[mt][nt] = __builtin_amdgcn_mfma_f32_16x16x32_bf16(a[mt][1], b[nt][1], acc[mt][nt], 0, 0, 0);
    __builtin_amdgcn_s_setprio(0);
    __builtin_amdgcn_s_barrier();

    if (t + 2 < nk) stageAB256(B, K, bn, (t + 2) * 64, sB, tid);
    G256_SYNC();
    __builtin_amdgcn_s_setprio(1);
#pragma unroll
    for (int nt = 0; nt < 4; ++nt)
#pragma unroll
      for (int mt = 4; mt < 8; ++mt)
        acc[mt][nt] = __builtin_amdgcn_mfma_f32_16x16x32_bf16(a[mt][1], b[nt][1], acc[mt][nt], 0, 0, 0);
    __builtin_amdgcn_s_setprio(0);
    if (t + 1 < nk) {
      if (t + 2 < nk) asm volatile("s_waitcnt vmcnt(8)" ::: "memory");
      else            asm volatile("s_waitcnt vmcnt(0)" ::: "memory");
      __builtin_amdgcn_s_barrier();
    }
  }

#pragma unroll
  for (int mt = 0; mt < 8; ++mt)
#pragma unroll
    for (int nt = 0; nt < 4; ++nt)
#pragma unroll
      for (int rr = 0; rr < 4; ++rr) {
        int row = bm + wr * 128 + mt * 16 + g * 4 + rr;
        int col = bn + wc * 64 + nt * 16 + li;
        C[(size_t)row * ldc + col] = f2bf(acc[mt][nt][rr]);
      }
}

// ---- merged prep: rmsnorm+rope (blocks <10240) | v-transpose (blocks >=10240)
__global__ void k_prep(const u16* __restrict__ qkv, const float* __restrict__ nqw,
                       const float* __restrict__ nkw, const float* __restrict__ fc,
                       u16* __restrict__ qh, u16* __restrict__ kh,
                       u16* __restrict__ vT) {
  __shared__ u16 t[128][65];
  int bid = blockIdx.x;
  if (bid < 10240) {
    int wid = threadIdx.x >> 6, lane = threadIdx.x & 63;
    int pair = bid * 4 + wid;               // 0 .. 40959
    int s = pair >> 4, hh = pair & 15;
    const u16* qrow = qkv + (size_t)s * 6144 + hh * 128;
    unsigned uq = *(const unsigned*)(qrow + lane * 2);
    unsigned uk = *(const unsigned*)(qrow + 2048 + lane * 2);
    float qx = bf2f(uq << 16), qy = bf2f(uq & 0xFFFF0000u);
    float kx = bf2f(uk << 16), ky = bf2f(uk & 0xFFFF0000u);
    float sq = qx * qx + qy * qy;
    float sk = kx * kx + ky * ky;
#pragma unroll
    for (int m = 32; m >= 1; m >>= 1) { sq += __shfl_xor(sq, m); sk += __shfl_xor(sk, m); }
    float rq = rsqrtf(sq * (1.f / 128.f) + 1e-5f);
    float rk = rsqrtf(sk * (1.f / 128.f) + 1e-5f);
    float2 wq2 = *(const float2*)(nqw + lane * 2);
    float2 wk2 = *(const float2*)(nkw + lane * 2);
    float2 cs = *(const float2*)(fc + (size_t)s * 128 + lane * 2);
    float q0 = qx * rq * wq2.x, q1 = qy * rq * wq2.y;
    float k0 = kx * rk * wk2.x, k1 = ky * rk * wk2.y;
    unsigned qo = (unsigned)f2bf(q0 * cs.x - q1 * cs.y) | ((unsigned)f2bf(q1 * cs.x + q0 * cs.y) << 16);
    unsigned ko = (unsigned)f2bf(k0 * cs.x - k1 * cs.y) | ((unsigned)f2bf(k1 * cs.x + k0 * cs.y) << 16);
    *(unsigned*)(qh + ((size_t)hh * NSEQ + s) * 128 + lane * 2) = qo;
    *(unsigned*)(kh + ((size_t)hh * NSEQ + s) * 128 + lane * 2) = ko;
    return;
  }
  int bx = bid - 10240;                      // 0..639: 40 s-blocks x 16 heads
  int s0 = (bx % 40) * 64, hh = bx / 40;
  int tid = threadIdx.x;
#pragma unroll
  for (int rep = 0; rep < 16; ++rep) {
    int idx = rep * 256 + tid;               // (row sr, u32-pair d2)
    int sr = idx >> 6, d2 = idx & 63;
    unsigned v2 = *(const unsigned*)(qkv + (size_t)(s0 + sr) * 6144 + 4096 + hh * 128 + d2 * 2);
    t[d2 * 2][sr] = (u16)v2;
    t[d2 * 2 + 1][sr] = (u16)(v2 >> 16);
  }
  __syncthreads();
#pragma unroll
  for (int rep = 0; rep < 16; ++rep) {
    int idx = rep * 256 + tid; int d = idx >> 5, sc2 = (idx & 31) * 2;
    unsigned val = (unsigned)t[d][sc2] | ((unsigned)t[d][sc2 + 1] << 16);
    *(unsigned*)(vT + ((size_t)hh * 128 + d) * NSEQ + s0 + sc2) = val;
  }
}

// ---- flash attention helpers ------------------------------------------------
// LDS (40960 B): K [64][128]swz @0 (16K) | vT [128][64]swz @16K (16K) | P @32K
__device__ __forceinline__ void stage_kv(const u16* __restrict__ khh,
                                         const u16* __restrict__ vTh,
                                         int kphys, unsigned char* sm,
                                         int lane, int wl) {
#pragma unroll
  for (int c = 0; c < 4; ++c) {
    int base = (wl * 4 + c) * 1024;
    { int row = (base >> 8) + (lane >> 4);                 // K tile: 64 rows x 256B
      int src = ((lane & 15) * 16) ^ ((row & 7) << 4);
      gload16((const char*)(khh + (size_t)(kphys + row) * 128) + src, sm + base); }
    { int row = (base >> 7) + (lane >> 3);                 // vT tile: 128 rows x 128B
      int src = ((lane & 7) * 16) ^ ((row & 7) << 4);
      gload16((const char*)(vTh + (size_t)row * NSEQ + kphys) + src, sm + 16384 + base); }
  }
}

// Swapped QK^T: sc[nt] = mfma(K_frag, Q_frag) -> sc[nt][r] = P[key=nt*16+g*4+r][q=li].
// Per-lane softmax state: mold is the running max for q = q0+li (scalar).
// o[0..7] = output d-columns (rows q=g*4+r), o[8] = denominator column.
__device__ __forceinline__ void tile_compute(unsigned char* sm, unsigned char* pb,
                                             const s8x (&aq)[4], int g, int li,
                                             f4x (&o)[9], float& mold) {
  const float S2 = 0.08838834764831845f * 1.4426950408889634f;  // scale*log2(e)
  const float THR_RAW = 90.0f;                 // ~8 in exp-arg units
  const s8x PONE = {16256, 16256, 16256, 16256, 16256, 16256, 16256, 16256}; // bf16 1.0
  const f4x zf = {0.f, 0.f, 0.f, 0.f};
  f4x sc[4];
#pragma unroll
  for (int nt = 0; nt < 4; ++nt) sc[nt] = zf;
  __builtin_amdgcn_s_setprio(1);
#pragma unroll
  for (int nt = 0; nt < 4; ++nt) {
    int row = nt * 16 + li;
    int rx = (row & 7) << 4;
#pragma unroll
    for (int ds = 0; ds < 4; ++ds) {
      s8x bk = *(const s8x*)(sm + row * 256 + ((ds * 64 + g * 16) ^ rx));
      sc[nt] = __builtin_amdgcn_mfma_f32_16x16x32_bf16(bk, aq[ds], sc[nt], 0, 0, 0);
    }
  }
  __builtin_amdgcn_s_setprio(0);

  // row-max for q=li: in-lane max of 16 + 2 shfl_xor across the 4 g-lanes
  float tl = fmaxf(fmaxf(fmaxf(sc[0][0], sc[0][1]), fmaxf(sc[0][2], sc[0][3])),
                   fmaxf(fmaxf(sc[1][0], sc[1][1]), fmaxf(sc[1][2], sc[1][3])));
  tl = fmaxf(tl, fmaxf(fmaxf(fmaxf(sc[2][0], sc[2][1]), fmaxf(sc[2][2], sc[2][3])),
                       fmaxf(fmaxf(sc[3][0], sc[3][1]), fmaxf(sc[3][2], sc[3][3]))));
  tl = fmaxf(tl, __shfl_xor(tl, 16));
  tl = fmaxf(tl, __shfl_xor(tl, 32));
  if (__any((int)(tl > mold + THR_RAW))) {     // rare rescale
    float mn = fmaxf(mold, tl);
    float corr = exp2f((mold - mn) * S2);      // corr for q = li (per-lane)
    mold = mn;
    float cf[4];
#pragma unroll
    for (int r = 0; r < 4; ++r)
      cf[r] = __shfl(corr, (g << 4) | (g * 4 + r));   // corr for o-row q=g*4+r
#pragma unroll
    for (int dt = 0; dt < 9; ++dt)
#pragma unroll
      for (int r = 0; r < 4; ++r) o[dt][r] *= cf[r];
  }
  float nb = -mold * S2;
#pragma unroll
  for (int nt = 0; nt < 4; ++nt) {             // P A-layout [16 q][64 key] swz
    u16 pp[4];
#pragma unroll
    for (int r = 0; r < 4; ++r) {
      float p = exp2f(fmaf(sc[nt][r], S2, nb));
      union { float f; unsigned u; } pv_; pv_.f = p;
      pp[r] = (u16)(pv_.u >> 16);              // truncation cancels in o/l
    }
    uint2 w;
    w.x = (unsigned)pp[0] | ((unsigned)pp[1] << 16);
    w.y = (unsigned)pp[2] | ((unsigned)pp[3] << 16);
    // row = li (q), keys nt*16+g*4 .. +3 -> 8B at byte (nt*32+g*8), swizzled
    *(uint2*)(pb + li * 128 + ((nt * 32 + g * 8) ^ ((li & 7) << 4))) = w;
  }
  __builtin_amdgcn_s_setprio(1);
#pragma unroll
  for (int ks = 0; ks < 2; ++ks) {
    s8x pa = *(const s8x*)(pb + li * 128 + ((ks * 64 + g * 16) ^ ((li & 7) << 4)));
#pragma unroll
    for (int dt = 0; dt < 8; ++dt) {
      int row = dt * 16 + li;
      s8x bv = *(const s8x*)(sm + 16384 + row * 128 + ((ks * 64 + g * 16) ^ ((row & 7) << 4)));
      o[dt] = __builtin_amdgcn_mfma_f32_16x16x32_bf16(pa, bv, o[dt], 0, 0, 0);
    }
    o[8] = __builtin_amdgcn_mfma_f32_16x16x32_bf16(pa, PONE, o[8], 0, 0, 0);
  }
  __builtin_amdgcn_s_setprio(0);
}

__device__ __forceinline__ void epilogue(u16* __restrict__ out, int q0, int hh,
                                         int g, int li, const f4x (&o)[9]) {
  float inv[4];
#pragma unroll
  for (int r = 0; r < 4; ++r) inv[r] = 1.f / o[8][r];
#pragma unroll
  for (int dt = 0; dt < 8; ++dt)
#pragma unroll
    for (int r = 0; r < 4; ++r) {
      int n = q0 + g * 4 + r;
      int col = hh * 128 + dt * 16 + li;
      out[(size_t)n * NDIM + col] = f2bf(o[dt][r] * inv[r]);
    }
}

// ---- fused pos/neg flash attention ------------------------------------------
// 640 blocks, 256 thr (4 waves), 64 q-rows/WG (16/wave). XCD x: heads {2x,2x+1}.
__global__ __launch_bounds__(256, 3)
void k_attn(const u16* __restrict__ qh, const u16* __restrict__ kh,
            const u16* __restrict__ vT, u16* __restrict__ xpos,
            u16* __restrict__ xneg) {
  __shared__ __align__(16) unsigned char sm[40960];
  const int lane = threadIdx.x & 63, wl = threadIdx.x >> 6;
  const int g = lane >> 4, li = lane & 15;

  const int s = blockIdx.x;            // 0..639
  const int xcd = s & 7, j = s >> 3;
  const int hh = 2 * xcd + (j & 1);
  const int u = j >> 1;                // 0..39
  const bool shared_blk = (u < 32);
  const int qb = shared_blk ? u : (32 + ((u - 32) >> 1));
  const int mode = shared_blk ? 0 : ((u - 32) & 1);
  const int q0 = qb * 64 + wl * 16;

  const u16* khh = kh + (size_t)hh * NSEQ * 128;
  const u16* vTh = vT + (size_t)hh * 128 * NSEQ;
  unsigned char* pb = sm + 32768 + wl * 2048;

  s8x aq[4];
  {
    int ql = q0 + li;
    int qp = (mode && ql >= 2048) ? ql + 256 : ql;
    const u16* base = qh + ((size_t)hh * NSEQ + qp) * 128 + g * 8;
#pragma unroll
    for (int ds = 0; ds < 4; ++ds) aq[ds] = *(const s8x*)(base + ds * 32);
  }

  const f4x zf = {0.f, 0.f, 0.f, 0.f};
  f4x o1[9];
  float m1 = -1e30f;
#pragma unroll
  for (int dt = 0; dt < 9; ++dt) o1[dt] = zf;

  const int n1 = shared_blk ? 32 : 36;
  for (int t = 0; t < n1; ++t) {
    int kphys = (mode && t >= 32) ? 2304 + (t - 32) * 64 : t * 64;
    stage_kv(khh, vTh, kphys, sm, lane, wl);
    __syncthreads();
    tile_compute(sm, pb, aq, g, li, o1, m1);
    __syncthreads();
  }

  if (shared_blk) {
    f4x o2[9];
    float m2 = m1;
#pragma unroll
    for (int dt = 0; dt < 9; ++dt) o2[dt] = o1[dt];
    for (int t = 0; t < 4; ++t) {              // pos tail: phys 2048..2303
      stage_kv(khh, vTh, 2048 + t * 64, sm, lane, wl);
      __syncthreads();
      tile_compute(sm, pb, aq, g, li, o1, m1);
      __syncthreads();
    }
    epilogue(xpos, q0, hh, g, li, o1);         // free o1 before neg tail
    for (int t = 0; t < 4; ++t) {              // neg tail: phys 2304..2559
      stage_kv(khh, vTh, 2304 + t * 64, sm, lane, wl);
      __syncthreads();
      tile_compute(sm, pb, aq, g, li, o2, m2);
      __syncthreads();
    }
    epilogue(xneg, q0, hh, g, li, o2);
  } else {
    epilogue(mode ? xneg : xpos, q0, hh, g, li, o1);
  }
}

// ---- NAG combine (bf16 in) + tail copy, bf16 X out --------------------------
__global__ void k_nag(const u16* __restrict__ xp, const u16* __restrict__ xn,
                      u16* __restrict__ X) {
  int n = blockIdx.x, t = threadIdx.x;
  if (n >= NSDPA) {   // rows 2304..2559 = x_neg rows 2048..2303 (raw copy)
    *(uint4*)(X + (size_t)n * NDIM + t * 8) =
        *(const uint4*)(xn + (size_t)(n - 256) * NDIM + t * 8);
    return;
  }
  uint4 up = *(const uint4*)(xp + (size_t)n * NDIM + t * 8);
  uint4 un = *(const uint4*)(xn + (size_t)n * NDIM + t * 8);
  unsigned wp[4] = {up.x, up.y, up.z, up.w};
  unsigned wn[4] = {un.x, un.y, un.z, un.w};
  float pv[8], nv[8], gv[8];
#pragma unroll
  for (int i = 0; i < 4; ++i) {
    pv[2 * i] = bf2f(wp[i] << 16);  pv[2 * i + 1] = bf2f(wp[i] & 0xFFFF0000u);
    nv[2 * i] = bf2f(wn[i] << 16);  nv[2 * i + 1] = bf2f(wn[i] & 0xFFFF0000u);
  }
  float sp = 0.f, sg = 0.f;
#pragma unroll
  for (int i = 0; i < 8; ++i) {
    float gq = 5.f * pv[i] - 4.f * nv[i];
    gv[i] = gq; sp += fabsf(pv[i]); sg += fabsf(gq);
  }
#pragma unroll
  for (int m = 32; m >= 1; m >>= 1) { sp += __shfl_xor(sp, m); sg += __shfl_xor(sg, m); }
  __shared__ float red[2][4];
  int wid = t >> 6, lane = t & 63;
  if (lane == 0) { red[0][wid] = sp; red[1][wid] = sg; }
  __syncthreads();
  float np_ = red[0][0] + red[0][1] + red[0][2] + red[0][3];
  float ng_ = red[1][0] + red[1][1] + red[1][2] + red[1][3];
  float ratio = ng_ / np_;
  if (isnan(ratio)) ratio = 10.f;
  float factor = np_ * 2.5f / (ng_ + 1e-7f);
  float mul = (ratio > 2.5f) ? factor : 1.f;
  uint4 p;
  u16 ob[8];
#pragma unroll
  for (int i = 0; i < 8; ++i) ob[i] = f2bf(gv[i] * mul * 0.25f + pv[i] * 0.75f);
  p.x = (unsigned)ob[0] | ((unsigned)ob[1] << 16);
  p.y = (unsigned)ob[2] | ((unsigned)ob[3] << 16);
  p.z = (unsigned)ob[4] | ((unsigned)ob[5] << 16);
  p.w = (unsigned)ob[6] | ((unsigned)ob[7] << 16);
  *(uint4*)(X + (size_t)n * NDIM + t * 8) = p;
}

// ---------------------------------------------------------------------------
extern "C" void kernel_launch(void* const* d_in, const int* in_sizes, int n_in,
                              void* d_out, int out_size, void* d_ws, size_t ws_size,
                              hipStream_t stream) {
  const float* h   = (const float*)d_in[0];
  const float* wq  = (const float*)d_in[1];
  const float* wk  = (const float*)d_in[2];
  const float* wv  = (const float*)d_in[3];
  const float* wo  = (const float*)d_in[4];
  const float* nqw = (const float*)d_in[5];
  const float* nkw = (const float*)d_in[6];
  const float* fc  = (const float*)d_in[7];
  (void)in_sizes; (void)n_in; (void)out_size; (void)ws_size;

  char* ws = (char*)d_ws;
  u16*   wB   = (u16*)ws;                                   // 4 * 2048*2048 bf16 (33.55 MB)
  u16*   hB   = (u16*)(ws + 33554432);                      // 2560*2048 bf16; later X
  u16*   qkvb = (u16*)(ws + 44040192);                      // 2560*6144 bf16 (31.5 MB)
  u16*   qh   = (u16*)(ws + 106954752);                     // 16*2560*128 bf16
  u16*   kh   = qh + (size_t)16 * 2560 * 128;
  u16*   vT   = kh + (size_t)16 * 2560 * 128;
  u16*   xpos = (u16*)(ws + 44040192);                      // alias (qkvb dead after k_prep)
  u16*   xneg = xpos + (size_t)NSDPA * NDIM;
  u16*   X    = hB;                                         // alias (hB dead after GEMM1)

  static bool attr_done = false;
  if (!attr_done) {
    hipFuncSetAttribute((const void*)k_gemm256,
                        hipFuncAttributeMaxDynamicSharedMemorySize, 131072);
    attr_done = true;
  }

  k_cast<<<10752, 256, 0, stream>>>(h, wq, wk, wv, wo, hB, wB);
  k_gemm256<<<240, 512, 131072, stream>>>(hB, wB, qkvb, 2048, 6144, 24);
  k_prep<<<10880, 256, 0, stream>>>(qkvb, nqw, nkw, fc, qh, kh, vT);
  k_attn<<<640, 256, 0, stream>>>(qh, kh, vT, xpos, xneg);
  k_nag<<<2560, 256, 0, stream>>>(xpos, xneg, X);
  k_gemm_bt<<<320, 256, 0, stream>>>(X, wB + 12582912, (float*)d_out, 2048, 2048, 16);
}

// Round 14
// 238.374 us; speedup vs baseline: 1.3395x; 1.0155x over previous
//
#include <hip/hip_runtime.h>
#include <stdint.h>

// ---------------------------------------------------------------------------
// Attention_53790170415368 : NAG dual-SDPA attention block, MI355X / gfx950
// R14: GEMM1 v-column blocks write vT directly (in-LDS 256x256 transpose in
//      the epilogue; LDS free after K-loop). k_prep loses its vtrans branch.
//      v values bit-identical to R13 (absmax fingerprint 0.001464844).
// ---------------------------------------------------------------------------

typedef short s8x __attribute__((ext_vector_type(8)));   // 8 x bf16 (raw bits)
typedef float f4x __attribute__((ext_vector_type(4)));
typedef unsigned short u16;

#define NDIM   2048
#define NHEAD  16
#define NHD    128
#define NSEQ   2560
#define NSDPA  2304

__device__ __forceinline__ u16 f2bf(float f) {
  union { float f; unsigned u; } v; v.f = f;
  unsigned r = v.u + 0x7FFFu + ((v.u >> 16) & 1u);   // RNE
  return (u16)(r >> 16);
}

__device__ __forceinline__ float bf2f(unsigned hi16_in_place) {
  union { unsigned u; float f; } v; v.u = hi16_in_place;
  return v.f;
}

__device__ __forceinline__ void gload16(const void* g, void* l) {
  __builtin_amdgcn_global_load_lds(
      (const __attribute__((address_space(1))) unsigned*)g,
      (__attribute__((address_space(3))) unsigned*)l, 16, 0, 0);
}

// ---- merged fp32 -> bf16 casts: h (2560 blks) + 4 weights (4x2048 blks) -----
__global__ void k_cast(const float* __restrict__ h, const float* __restrict__ w0,
                       const float* __restrict__ w1, const float* __restrict__ w2,
                       const float* __restrict__ w3, u16* __restrict__ hB,
                       u16* __restrict__ wB) {
  int bid = blockIdx.x;
  const float* src; u16* dst; int i;
  if (bid < 2560) {                       // h: 655360 groups of 8
    src = h; dst = hB; i = bid * 256 + threadIdx.x;
  } else {
    int b = bid - 2560;
    int m = b >> 11;                      // /2048
    i = (b & 2047) * 256 + threadIdx.x;   // 0..524287
    src = (m == 0) ? w0 : (m == 1) ? w1 : (m == 2) ? w2 : w3;
    dst = wB + (size_t)m * 4194304;
  }
  const float4* s4 = (const float4*)src + (size_t)i * 2;
  float4 a = s4[0], b4 = s4[1];
  uint4 p;
  p.x = (unsigned)f2bf(a.x) | ((unsigned)f2bf(a.y) << 16);
  p.y = (unsigned)f2bf(a.z) | ((unsigned)f2bf(a.w) << 16);
  p.z = (unsigned)f2bf(b4.x) | ((unsigned)f2bf(b4.y) << 16);
  p.w = (unsigned)f2bf(b4.z) | ((unsigned)f2bf(b4.w) << 16);
  *(uint4*)(dst + (size_t)i * 8) = p;
}

// ---- C[M,N] f32 = A[M,K]bf16 @ B[N,K]bf16^T  (m97, 128x128, XCD swizzle) ----
__global__ __launch_bounds__(256, 2)
void k_gemm_bt(const u16* __restrict__ A, const u16* __restrict__ B,
               float* __restrict__ C, int K, int ldc, int nbn) {
  __shared__ __align__(16) unsigned char sm[16384];  // A tile 8K | B tile 8K
  const int cpx = gridDim.x >> 3;
  const int f = blockIdx.x;
  const int swz = (f & 7) * cpx + (f >> 3);          // bijective: grid % 8 == 0
  const int bm = (swz / nbn) * 128, bn = (swz % nbn) * 128;
  const int lane = threadIdx.x & 63, wl = threadIdx.x >> 6;
  const int wm = wl >> 1, wn = wl & 1;
  const int g = lane >> 4, li = lane & 15;
  f4x acc[4][4] = {};
  const int nk = K >> 5;
  for (int kk = 0; kk < nk; ++kk) {
#pragma unroll
    for (int c = 0; c < 2; ++c) {
      int base = (wl * 2 + c) * 1024;
      int row = (base >> 6) + (lane >> 2);
      int colb = (lane & 3) * 16;
      gload16((const char*)A + ((size_t)(bm + row) * K + kk * 32) * 2 + colb, sm + base);
      gload16((const char*)B + ((size_t)(bn + row) * K + kk * 32) * 2 + colb, sm + 8192 + base);
    }
    __syncthreads();
    s8x a[4];
#pragma unroll
    for (int mt = 0; mt < 4; ++mt)
      a[mt] = *(const s8x*)(sm + (wm * 64 + mt * 16 + li) * 64 + g * 16);
#pragma unroll
    for (int nt = 0; nt < 4; ++nt) {
      s8x b = *(const s8x*)(sm + 8192 + (wn * 64 + nt * 16 + li) * 64 + g * 16);
#pragma unroll
      for (int mt = 0; mt < 4; ++mt)
        acc[mt][nt] = __builtin_amdgcn_mfma_f32_16x16x32_bf16(a[mt], b, acc[mt][nt], 0, 0, 0);
    }
    __syncthreads();
  }
#pragma unroll
  for (int mt = 0; mt < 4; ++mt)
#pragma unroll
    for (int nt = 0; nt < 4; ++nt)
#pragma unroll
      for (int r = 0; r < 4; ++r) {
        int row = bm + wm * 64 + mt * 16 + g * 4 + r;
        int col = bn + wn * 64 + nt * 16 + li;
        C[(size_t)row * ldc + col] = acc[mt][nt][r];
      }
}

// ---- 256x256 tile, BK=64, 8 waves (2Mx4N), 128KB LDS dbuf, 4-phase/tile -----
// q/k cols -> bf16 qkvb; v cols (bn>=4096) -> in-LDS transpose -> vT direct.
__device__ __forceinline__ void stageAB256(const u16* __restrict__ M, int K,
                                           int row0, int kk, unsigned char* dst,
                                           int tid) {
#pragma unroll
  for (int c = 0; c < 4; ++c) {
    int idx = c * 512 + tid;                 // chunk 0..2047 (row r, chunk idx&7)
    int r = idx >> 3, cc = idx & 7;
    gload16(M + (size_t)(row0 + r) * K + kk + ((cc ^ (r & 7)) * 8), dst + idx * 16);
  }
}

#define G256_SYNC() do { __builtin_amdgcn_s_barrier();                        \
    asm volatile("s_waitcnt lgkmcnt(0)" ::: "memory");                        \
    __builtin_amdgcn_sched_barrier(0); } while (0)

__global__ __launch_bounds__(512, 2)
void k_gemm256(const u16* __restrict__ A, const u16* __restrict__ B,
               u16* __restrict__ C, u16* __restrict__ vT,
               int K, int ldc, int nbn) {
  extern __shared__ __align__(16) unsigned char sm[];     // 131072
  const int tid = threadIdx.x;
  const int lane = tid & 63, wid = tid >> 6;
  const int g = lane >> 4, li = lane & 15;
  const int wr = wid >> 2, wc = wid & 3;

  const int cpx = gridDim.x >> 3;
  const int f = blockIdx.x;
  const int swz = (f & 7) * cpx + (f >> 3);
  const int bm = (swz / nbn) * 256, bn = (swz % nbn) * 256;

  f4x acc[8][4] = {};
  const int nk = K >> 6;

  stageAB256(A, K, bm, 0, sm, tid);
  stageAB256(B, K, bn, 0, sm + 32768, tid);
  stageAB256(A, K, bm, 64, sm + 65536, tid);
  stageAB256(B, K, bn, 64, sm + 98304, tid);
  asm volatile("s_waitcnt vmcnt(8)" ::: "memory");
  __builtin_amdgcn_s_barrier();

  for (int t = 0; t < nk; ++t) {
    unsigned char* sA = sm + (t & 1) * 65536;
    unsigned char* sB = sA + 32768;
    s8x a[8][2], b[4][2];

#pragma unroll
    for (int mt = 0; mt < 4; ++mt) {
      int r = wr * 128 + mt * 16 + li;
#pragma unroll
      for (int ks = 0; ks < 2; ++ks)
        a[mt][ks] = *(const s8x*)(sA + r * 128 + (((ks * 4 + g) ^ (r & 7)) * 16));
    }
#pragma unroll
    for (int nt = 0; nt < 4; ++nt) {
      int r = wc * 64 + nt * 16 + li;
      b[nt][0] = *(const s8x*)(sB + r * 128 + ((g ^ (r & 7)) * 16));
    }
    G256_SYNC();
    __builtin_amdgcn_s_setprio(1);
#pragma unroll
    for (int nt = 0; nt < 4; ++nt)
#pragma unroll
      for (int mt = 0; mt < 4; ++mt)
        acc[mt][nt] = __builtin_amdgcn_mfma_f32_16x16x32_bf16(a[mt][0], b[nt][0], acc[mt][nt], 0, 0, 0);
    __builtin_amdgcn_s_setprio(0);
    __builtin_amdgcn_s_barrier();

#pragma unroll
    for (int mt = 4; mt < 8; ++mt) {
      int r = wr * 128 + mt * 16 + li;
#pragma unroll
      for (int ks = 0; ks < 2; ++ks)
        a[mt][ks] = *(const s8x*)(sA + r * 128 + (((ks * 4 + g) ^ (r & 7)) * 16));
    }
#pragma unroll
    for (int nt = 0; nt < 4; ++nt) {
      int r = wc * 64 + nt * 16 + li;
      b[nt][1] = *(const s8x*)(sB + r * 128 + (((4 + g) ^ (r & 7)) * 16));
    }
    G256_SYNC();
    __builtin_amdgcn_s_setprio(1);
#pragma unroll
    for (int nt = 0; nt < 4; ++nt)
#pragma unroll
      for (int mt = 4; mt < 8; ++mt)
        acc[mt][nt] = __builtin_amdgcn_mfma_f32_16x16x32_bf16(a[mt][0], b[nt][0], acc[mt][nt], 0, 0, 0);
    __builtin_amdgcn_s_setprio(0);
    __builtin_amdgcn_s_barrier();

    if (t + 2 < nk) stageAB256(A, K, bm, (t + 2) * 64, sA, tid);
    G256_SYNC();
    __builtin_amdgcn_s_setprio(1);
#pragma unroll
    for (int nt = 0; nt < 4; ++nt)
#pragma unroll
      for (int mt = 0; mt < 4; ++mt)
        acc[mt][nt] = __builtin_amdgcn_mfma_f32_16x16x32_bf16(a[mt][1], b[nt][1], acc[mt][nt], 0, 0, 0);
    __builtin_amdgcn_s_setprio(0);
    __builtin_amdgcn_s_barrier();

    if (t + 2 < nk) stageAB256(B, K, bn, (t + 2) * 64, sB, tid);
    G256_SYNC();
    __builtin_amdgcn_s_setprio(1);
#pragma unroll
    for (int nt = 0; nt < 4; ++nt)
#pragma unroll
      for (int mt = 4; mt < 8; ++mt)
        acc[mt][nt] = __builtin_amdgcn_mfma_f32_16x16x32_bf16(a[mt][1], b[nt][1], acc[mt][nt], 0, 0, 0);
    __builtin_amdgcn_s_setprio(0);
    if (t + 1 < nk) {
      if (t + 2 < nk) asm volatile("s_waitcnt vmcnt(8)" ::: "memory");
      else            asm volatile("s_waitcnt vmcnt(0)" ::: "memory");
      __builtin_amdgcn_s_barrier();
    }
  }

  if (bn < 4096) {                           // q/k columns -> qkvb (bf16)
#pragma unroll
    for (int mt = 0; mt < 8; ++mt)
#pragma unroll
      for (int nt = 0; nt < 4; ++nt)
#pragma unroll
        for (int rr = 0; rr < 4; ++rr) {
          int row = bm + wr * 128 + mt * 16 + g * 4 + rr;
          int col = bn + wc * 64 + nt * 16 + li;
          C[(size_t)row * ldc + col] = f2bf(acc[mt][nt][rr]);
        }
  } else {                                   // v columns -> in-LDS transpose -> vT
    __syncthreads();                         // main-loop LDS reads complete
#pragma unroll
    for (int mt = 0; mt < 8; ++mt)
#pragma unroll
      for (int nt = 0; nt < 4; ++nt) {
        int col = wc * 64 + nt * 16 + li;    // local d-col 0..255
        int rowb = (wr * 128 + mt * 16 + g * 4) * 2;   // byte offset of row
        u16 pk[4];
#pragma unroll
        for (int rr = 0; rr < 4; ++rr) pk[rr] = f2bf(acc[mt][nt][rr]);
        uint2 w;
        w.x = (unsigned)pk[0] | ((unsigned)pk[1] << 16);
        w.y = (unsigned)pk[2] | ((unsigned)pk[3] << 16);
        *(uint2*)(sm + col * 512 + (rowb ^ ((col & 7) << 4))) = w;
      }
    __syncthreads();
    const int hbase = (bn - 4096) >> 7;      // first head in this block (2 total)
#pragma unroll
    for (int c = 0; c < 16; ++c) {
      int idx = c * 512 + tid;               // 0..8191: (col, 16B row-chunk)
      int col = idx >> 5, ch = idx & 31;
      uint4 v = *(const uint4*)(sm + col * 512 + ((ch * 16) ^ ((col & 7) << 4)));
      int hh = hbase + (col >> 7);
      int d = col & 127;
      *(uint4*)(vT + ((size_t)hh * 128 + d) * NSEQ + bm + ch * 8) = v;
    }
  }
}

// ---- rmsnorm + rope for q,k (bf16 qkvb in) ; head-major bf16 out ------------
__global__ void k_prep(const u16* __restrict__ qkv, const float* __restrict__ nqw,
                       const float* __restrict__ nkw, const float* __restrict__ fc,
                       u16* __restrict__ qh, u16* __restrict__ kh) {
  int wid = threadIdx.x >> 6, lane = threadIdx.x & 63;
  int pair = blockIdx.x * 4 + wid;          // 0 .. 40959
  int s = pair >> 4, hh = pair & 15;
  const u16* qrow = qkv + (size_t)s * 6144 + hh * 128;
  unsigned uq = *(const unsigned*)(qrow + lane * 2);
  unsigned uk = *(const unsigned*)(qrow + 2048 + lane * 2);
  float qx = bf2f(uq << 16), qy = bf2f(uq & 0xFFFF0000u);
  float kx = bf2f(uk << 16), ky = bf2f(uk & 0xFFFF0000u);
  float sq = qx * qx + qy * qy;
  float sk = kx * kx + ky * ky;
#pragma unroll
  for (int m = 32; m >= 1; m >>= 1) { sq += __shfl_xor(sq, m); sk += __shfl_xor(sk, m); }
  float rq = rsqrtf(sq * (1.f / 128.f) + 1e-5f);
  float rk = rsqrtf(sk * (1.f / 128.f) + 1e-5f);
  float2 wq2 = *(const float2*)(nqw + lane * 2);
  float2 wk2 = *(const float2*)(nkw + lane * 2);
  float2 cs = *(const float2*)(fc + (size_t)s * 128 + lane * 2);
  float q0 = qx * rq * wq2.x, q1 = qy * rq * wq2.y;
  float k0 = kx * rk * wk2.x, k1 = ky * rk * wk2.y;
  unsigned qo = (unsigned)f2bf(q0 * cs.x - q1 * cs.y) | ((unsigned)f2bf(q1 * cs.x + q0 * cs.y) << 16);
  unsigned ko = (unsigned)f2bf(k0 * cs.x - k1 * cs.y) | ((unsigned)f2bf(k1 * cs.x + k0 * cs.y) << 16);
  *(unsigned*)(qh + ((size_t)hh * NSEQ + s) * 128 + lane * 2) = qo;
  *(unsigned*)(kh + ((size_t)hh * NSEQ + s) * 128 + lane * 2) = ko;
}

// ---- flash attention helpers ------------------------------------------------
// LDS (40960 B): K [64][128]swz @0 (16K) | vT [128][64]swz @16K (16K) | P @32K
__device__ __forceinline__ void stage_kv(const u16* __restrict__ khh,
                                         const u16* __restrict__ vTh,
                                         int kphys, unsigned char* sm,
                                         int lane, int wl) {
#pragma unroll
  for (int c = 0; c < 4; ++c) {
    int base = (wl * 4 + c) * 1024;
    { int row = (base >> 8) + (lane >> 4);                 // K tile: 64 rows x 256B
      int src = ((lane & 15) * 16) ^ ((row & 7) << 4);
      gload16((const char*)(khh + (size_t)(kphys + row) * 128) + src, sm + base); }
    { int row = (base >> 7) + (lane >> 3);                 // vT tile: 128 rows x 128B
      int src = ((lane & 7) * 16) ^ ((row & 7) << 4);
      gload16((const char*)(vTh + (size_t)row * NSEQ + kphys) + src, sm + 16384 + base); }
  }
}

// Swapped QK^T: sc[nt][r] = P[key=nt*16+g*4+r][q=li]; per-lane scalar mold.
__device__ __forceinline__ void tile_compute(unsigned char* sm, unsigned char* pb,
                                             const s8x (&aq)[4], int g, int li,
                                             f4x (&o)[9], float& mold) {
  const float S2 = 0.08838834764831845f * 1.4426950408889634f;  // scale*log2(e)
  const float THR_RAW = 90.0f;                 // ~8 in exp-arg units
  const s8x PONE = {16256, 16256, 16256, 16256, 16256, 16256, 16256, 16256}; // bf16 1.0
  const f4x zf = {0.f, 0.f, 0.f, 0.f};
  f4x sc[4];
#pragma unroll
  for (int nt = 0; nt < 4; ++nt) sc[nt] = zf;
  __builtin_amdgcn_s_setprio(1);
#pragma unroll
  for (int nt = 0; nt < 4; ++nt) {
    int row = nt * 16 + li;
    int rx = (row & 7) << 4;
#pragma unroll
    for (int ds = 0; ds < 4; ++ds) {
      s8x bk = *(const s8x*)(sm + row * 256 + ((ds * 64 + g * 16) ^ rx));
      sc[nt] = __builtin_amdgcn_mfma_f32_16x16x32_bf16(bk, aq[ds], sc[nt], 0, 0, 0);
    }
  }
  __builtin_amdgcn_s_setprio(0);

  float tl = fmaxf(fmaxf(fmaxf(sc[0][0], sc[0][1]), fmaxf(sc[0][2], sc[0][3])),
                   fmaxf(fmaxf(sc[1][0], sc[1][1]), fmaxf(sc[1][2], sc[1][3])));
  tl = fmaxf(tl, fmaxf(fmaxf(fmaxf(sc[2][0], sc[2][1]), fmaxf(sc[2][2], sc[2][3])),
                       fmaxf(fmaxf(sc[3][0], sc[3][1]), fmaxf(sc[3][2], sc[3][3]))));
  tl = fmaxf(tl, __shfl_xor(tl, 16));
  tl = fmaxf(tl, __shfl_xor(tl, 32));
  if (__any((int)(tl > mold + THR_RAW))) {     // rare rescale
    float mn = fmaxf(mold, tl);
    float corr = exp2f((mold - mn) * S2);      // corr for q = li (per-lane)
    mold = mn;
    float cf[4];
#pragma unroll
    for (int r = 0; r < 4; ++r)
      cf[r] = __shfl(corr, (g << 4) | (g * 4 + r));   // corr for o-row q=g*4+r
#pragma unroll
    for (int dt = 0; dt < 9; ++dt)
#pragma unroll
      for (int r = 0; r < 4; ++r) o[dt][r] *= cf[r];
  }
  float nb = -mold * S2;
#pragma unroll
  for (int nt = 0; nt < 4; ++nt) {             // P A-layout [16 q][64 key] swz
    u16 pp[4];
#pragma unroll
    for (int r = 0; r < 4; ++r) {
      float p = exp2f(fmaf(sc[nt][r], S2, nb));
      union { float f; unsigned u; } pv_; pv_.f = p;
      pp[r] = (u16)(pv_.u >> 16);              // truncation cancels in o/l
    }
    uint2 w;
    w.x = (unsigned)pp[0] | ((unsigned)pp[1] << 16);
    w.y = (unsigned)pp[2] | ((unsigned)pp[3] << 16);
    *(uint2*)(pb + li * 128 + ((nt * 32 + g * 8) ^ ((li & 7) << 4))) = w;
  }
  __builtin_amdgcn_s_setprio(1);
#pragma unroll
  for (int ks = 0; ks < 2; ++ks) {
    s8x pa = *(const s8x*)(pb + li * 128 + ((ks * 64 + g * 16) ^ ((li & 7) << 4)));
#pragma unroll
    for (int dt = 0; dt < 8; ++dt) {
      int row = dt * 16 + li;
      s8x bv = *(const s8x*)(sm + 16384 + row * 128 + ((ks * 64 + g * 16) ^ ((row & 7) << 4)));
      o[dt] = __builtin_amdgcn_mfma_f32_16x16x32_bf16(pa, bv, o[dt], 0, 0, 0);
    }
    o[8] = __builtin_amdgcn_mfma_f32_16x16x32_bf16(pa, PONE, o[8], 0, 0, 0);
  }
  __builtin_amdgcn_s_setprio(0);
}

__device__ __forceinline__ void epilogue(u16* __restrict__ out, int q0, int hh,
                                         int g, int li, const f4x (&o)[9]) {
  float inv[4];
#pragma unroll
  for (int r = 0; r < 4; ++r) inv[r] = 1.f / o[8][r];
#pragma unroll
  for (int dt = 0; dt < 8; ++dt)
#pragma unroll
    for (int r = 0; r < 4; ++r) {
      int n = q0 + g * 4 + r;
      int col = hh * 128 + dt * 16 + li;
      out[(size_t)n * NDIM + col] = f2bf(o[dt][r] * inv[r]);
    }
}

// ---- fused pos/neg flash attention ------------------------------------------
// 640 blocks, 256 thr (4 waves), 64 q-rows/WG (16/wave). XCD x: heads {2x,2x+1}.
__global__ __launch_bounds__(256, 3)
void k_attn(const u16* __restrict__ qh, const u16* __restrict__ kh,
            const u16* __restrict__ vT, u16* __restrict__ xpos,
            u16* __restrict__ xneg) {
  __shared__ __align__(16) unsigned char sm[40960];
  const int lane = threadIdx.x & 63, wl = threadIdx.x >> 6;
  const int g = lane >> 4, li = lane & 15;

  const int s = blockIdx.x;            // 0..639
  const int xcd = s & 7, j = s >> 3;
  const int hh = 2 * xcd + (j & 1);
  const int u = j >> 1;                // 0..39
  const bool shared_blk = (u < 32);
  const int qb = shared_blk ? u : (32 + ((u - 32) >> 1));
  const int mode = shared_blk ? 0 : ((u - 32) & 1);
  const int q0 = qb * 64 + wl * 16;

  const u16* khh = kh + (size_t)hh * NSEQ * 128;
  const u16* vTh = vT + (size_t)hh * 128 * NSEQ;
  unsigned char* pb = sm + 32768 + wl * 2048;

  s8x aq[4];
  {
    int ql = q0 + li;
    int qp = (mode && ql >= 2048) ? ql + 256 : ql;
    const u16* base = qh + ((size_t)hh * NSEQ + qp) * 128 + g * 8;
#pragma unroll
    for (int ds = 0; ds < 4; ++ds) aq[ds] = *(const s8x*)(base + ds * 32);
  }

  const f4x zf = {0.f, 0.f, 0.f, 0.f};
  f4x o1[9];
  float m1 = -1e30f;
#pragma unroll
  for (int dt = 0; dt < 9; ++dt) o1[dt] = zf;

  const int n1 = shared_blk ? 32 : 36;
  for (int t = 0; t < n1; ++t) {
    int kphys = (mode && t >= 32) ? 2304 + (t - 32) * 64 : t * 64;
    stage_kv(khh, vTh, kphys, sm, lane, wl);
    __syncthreads();
    tile_compute(sm, pb, aq, g, li, o1, m1);
    __syncthreads();
  }

  if (shared_blk) {
    f4x o2[9];
    float m2 = m1;
#pragma unroll
    for (int dt = 0; dt < 9; ++dt) o2[dt] = o1[dt];
    for (int t = 0; t < 4; ++t) {              // pos tail: phys 2048..2303
      stage_kv(khh, vTh, 2048 + t * 64, sm, lane, wl);
      __syncthreads();
      tile_compute(sm, pb, aq, g, li, o1, m1);
      __syncthreads();
    }
    epilogue(xpos, q0, hh, g, li, o1);         // free o1 before neg tail
    for (int t = 0; t < 4; ++t) {              // neg tail: phys 2304..2559
      stage_kv(khh, vTh, 2304 + t * 64, sm, lane, wl);
      __syncthreads();
      tile_compute(sm, pb, aq, g, li, o2, m2);
      __syncthreads();
    }
    epilogue(xneg, q0, hh, g, li, o2);
  } else {
    epilogue(mode ? xneg : xpos, q0, hh, g, li, o1);
  }
}

// ---- NAG combine (bf16 in) + tail copy, bf16 X out --------------------------
__global__ void k_nag(const u16* __restrict__ xp, const u16* __restrict__ xn,
                      u16* __restrict__ X) {
  int n = blockIdx.x, t = threadIdx.x;
  if (n >= NSDPA) {   // rows 2304..2559 = x_neg rows 2048..2303 (raw copy)
    *(uint4*)(X + (size_t)n * NDIM + t * 8) =
        *(const uint4*)(xn + (size_t)(n - 256) * NDIM + t * 8);
    return;
  }
  uint4 up = *(const uint4*)(xp + (size_t)n * NDIM + t * 8);
  uint4 un = *(const uint4*)(xn + (size_t)n * NDIM + t * 8);
  unsigned wp[4] = {up.x, up.y, up.z, up.w};
  unsigned wn[4] = {un.x, un.y, un.z, un.w};
  float pv[8], nv[8], gv[8];
#pragma unroll
  for (int i = 0; i < 4; ++i) {
    pv[2 * i] = bf2f(wp[i] << 16);  pv[2 * i + 1] = bf2f(wp[i] & 0xFFFF0000u);
    nv[2 * i] = bf2f(wn[i] << 16);  nv[2 * i + 1] = bf2f(wn[i] & 0xFFFF0000u);
  }
  float sp = 0.f, sg = 0.f;
#pragma unroll
  for (int i = 0; i < 8; ++i) {
    float gq = 5.f * pv[i] - 4.f * nv[i];
    gv[i] = gq; sp += fabsf(pv[i]); sg += fabsf(gq);
  }
#pragma unroll
  for (int m = 32; m >= 1; m >>= 1) { sp += __shfl_xor(sp, m); sg += __shfl_xor(sg, m); }
  __shared__ float red[2][4];
  int wid = t >> 6, lane = t & 63;
  if (lane == 0) { red[0][wid] = sp; red[1][wid] = sg; }
  __syncthreads();
  float np_ = red[0][0] + red[0][1] + red[0][2] + red[0][3];
  float ng_ = red[1][0] + red[1][1] + red[1][2] + red[1][3];
  float ratio = ng_ / np_;
  if (isnan(ratio)) ratio = 10.f;
  float factor = np_ * 2.5f / (ng_ + 1e-7f);
  float mul = (ratio > 2.5f) ? factor : 1.f;
  uint4 p;
  u16 ob[8];
#pragma unroll
  for (int i = 0; i < 8; ++i) ob[i] = f2bf(gv[i] * mul * 0.25f + pv[i] * 0.75f);
  p.x = (unsigned)ob[0] | ((unsigned)ob[1] << 16);
  p.y = (unsigned)ob[2] | ((unsigned)ob[3] << 16);
  p.z = (unsigned)ob[4] | ((unsigned)ob[5] << 16);
  p.w = (unsigned)ob[6] | ((unsigned)ob[7] << 16);
  *(uint4*)(X + (size_t)n * NDIM + t * 8) = p;
}

// ---------------------------------------------------------------------------
extern "C" void kernel_launch(void* const* d_in, const int* in_sizes, int n_in,
                              void* d_out, int out_size, void* d_ws, size_t ws_size,
                              hipStream_t stream) {
  const float* h   = (const float*)d_in[0];
  const float* wq  = (const float*)d_in[1];
  const float* wk  = (const float*)d_in[2];
  const float* wv  = (const float*)d_in[3];
  const float* wo  = (const float*)d_in[4];
  const float* nqw = (const float*)d_in[5];
  const float* nkw = (const float*)d_in[6];
  const float* fc  = (const float*)d_in[7];
  (void)in_sizes; (void)n_in; (void)out_size; (void)ws_size;

  char* ws = (char*)d_ws;
  u16*   wB   = (u16*)ws;                                   // 4 * 2048*2048 bf16 (33.55 MB)
  u16*   hB   = (u16*)(ws + 33554432);                      // 2560*2048 bf16; later X
  u16*   qkvb = (u16*)(ws + 44040192);                      // 2560*6144 bf16 (q,k parts used)
  u16*   qh   = (u16*)(ws + 106954752);                     // 16*2560*128 bf16
  u16*   kh   = qh + (size_t)16 * 2560 * 128;
  u16*   vT   = kh + (size_t)16 * 2560 * 128;
  u16*   xpos = (u16*)(ws + 44040192);                      // alias (qkvb dead after k_prep)
  u16*   xneg = xpos + (size_t)NSDPA * NDIM;
  u16*   X    = hB;                                         // alias (hB dead after GEMM1)

  static bool attr_done = false;
  if (!attr_done) {
    hipFuncSetAttribute((const void*)k_gemm256,
                        hipFuncAttributeMaxDynamicSharedMemorySize, 131072);
    attr_done = true;
  }

  k_cast<<<10752, 256, 0, stream>>>(h, wq, wk, wv, wo, hB, wB);
  k_gemm256<<<240, 512, 131072, stream>>>(hB, wB, qkvb, vT, 2048, 6144, 24);
  k_prep<<<10240, 256, 0, stream>>>(qkvb, nqw, nkw, fc, qh, kh);
  k_attn<<<640, 256, 0, stream>>>(qh, kh, vT, xpos, xneg);
  k_nag<<<2560, 256, 0, stream>>>(xpos, xneg, X);
  k_gemm_bt<<<320, 256, 0, stream>>>(X, wB + 12582912, (float*)d_out, 2048, 2048, 16);
}